// Round 1
// baseline (2005.033 us; speedup 1.0000x reference)
//
#include <hip/hip_runtime.h>

#define N_USERS 90000
#define N_ITEMS 60000
#define NN      (N_USERS + N_ITEMS)   // 150000
#define D       64
#define KDIM    128
#define NE      1600000
#define EPSF    1e-12f
#define NB      ((NN + 255) / 256)    // 586 blocks for scans

// ---------------- CSR build ----------------

__global__ void k_deg(const int* __restrict__ h, int* __restrict__ deg) {
    int e = blockIdx.x * blockDim.x + threadIdx.x;
    if (e < NE) atomicAdd(&deg[h[e]], 1);
}

__global__ void k_blk_sum(const int* __restrict__ deg, int* __restrict__ blk) {
    __shared__ int s[4];
    int i = blockIdx.x * 256 + threadIdx.x;
    int v = (i < NN) ? deg[i] : 0;
    for (int off = 32; off; off >>= 1) v += __shfl_xor(v, off);
    if ((threadIdx.x & 63) == 0) s[threadIdx.x >> 6] = v;
    __syncthreads();
    if (threadIdx.x == 0) blk[blockIdx.x] = s[0] + s[1] + s[2] + s[3];
}

__global__ void k_scan_blk(int* __restrict__ blk) {
    __shared__ int s[1024];
    int t = threadIdx.x;
    int v = (t < NB) ? blk[t] : 0;
    s[t] = v;
    __syncthreads();
    for (int off = 1; off < 1024; off <<= 1) {
        int u = (t >= off) ? s[t - off] : 0;
        __syncthreads();
        s[t] += u;
        __syncthreads();
    }
    if (t < NB) blk[t] = (t == 0) ? 0 : s[t - 1];
}

__global__ void k_scan_final(const int* __restrict__ deg, const int* __restrict__ blk,
                             int* __restrict__ row_off, float* __restrict__ d_inv) {
    __shared__ int s[256];
    int t = threadIdx.x;
    int i = blockIdx.x * 256 + t;
    int v = (i < NN) ? deg[i] : 0;
    s[t] = v;
    __syncthreads();
    for (int off = 1; off < 256; off <<= 1) {
        int u = (t >= off) ? s[t - off] : 0;
        __syncthreads();
        s[t] += u;
        __syncthreads();
    }
    if (i < NN) {
        row_off[i] = blk[blockIdx.x] + s[t] - v;
        d_inv[i]   = (v > 0) ? rsqrtf((float)v) : 0.f;
    }
    if (i == 0) row_off[NN] = NE;
}

__global__ void k_scatter(const int* __restrict__ h, const int* __restrict__ t,
                          const int* __restrict__ row_off, int* __restrict__ row_cur,
                          const float* __restrict__ d_inv,
                          int* __restrict__ csr_t, float* __restrict__ csr_gv) {
    int e = blockIdx.x * blockDim.x + threadIdx.x;
    if (e >= NE) return;
    int hh = h[e], tt = t[e];
    int slot = row_off[hh] + atomicAdd(&row_cur[hh], 1);
    csr_t[slot]  = tt;
    csr_gv[slot] = d_inv[hh] * d_inv[tt];
}

// ---------------- init ----------------

__global__ void k_init(const float* __restrict__ emb, float* __restrict__ x0,
                       float* __restrict__ acc) {
    int i = blockIdx.x * blockDim.x + threadIdx.x;   // over NN*D/4 float4s
    float4 v = ((const float4*)emb)[i];
    ((float4*)x0)[i]  = v;
    ((float4*)acc)[i] = v;
}

// ---------------- per-layer kernels ----------------

// wave-per-row SPMM: gnn[r] = sum_e gv[e]*x[t[e]]; fused row L2-norm -> rn_g
__global__ __launch_bounds__(256) void k_gnn(const int* __restrict__ row_off,
                                             const int* __restrict__ csr_t,
                                             const float* __restrict__ csr_gv,
                                             const float* __restrict__ x,
                                             float* __restrict__ gnn,
                                             float* __restrict__ rn_g) {
    int wid  = (blockIdx.x * blockDim.x + threadIdx.x) >> 6;
    int lane = threadIdx.x & 63;
    if (wid >= NN) return;
    int e = row_off[wid], eend = row_off[wid + 1];
    float acc = 0.f;
    for (; e + 1 < eend; e += 2) {
        int   t0 = csr_t[e],  t1 = csr_t[e + 1];
        float g0 = csr_gv[e], g1 = csr_gv[e + 1];
        acc = fmaf(g0, x[t0 * D + lane], acc);
        acc = fmaf(g1, x[t1 * D + lane], acc);
    }
    if (e < eend) acc = fmaf(csr_gv[e], x[csr_t[e] * D + lane], acc);
    gnn[wid * D + lane] = acc;
    float ss = acc * acc;
    for (int off = 32; off; off >>= 1) ss += __shfl_xor(ss, off);
    if (lane == 0) rn_g[wid] = 1.f / fmaxf(sqrtf(ss), EPSF);
}

// wave-per-node intent projection: out = softmax(x@W) @ W^T ; fused rn_i
__global__ __launch_bounds__(256) void k_intent(const float* __restrict__ x,
                                                const float* __restrict__ W,
                                                float* __restrict__ intl,
                                                float* __restrict__ rn_i,
                                                int base, int count) {
    __shared__ float Ws[D][KDIM + 1];   // padded: conflict-free both phases
    __shared__ float xs[4][D];
    __shared__ float ps[4][KDIM];
    int tid = threadIdx.x, wv = tid >> 6, lane = tid & 63;
    for (int i = tid; i < D * KDIM; i += 256) Ws[i >> 7][i & 127] = W[i];
    __syncthreads();
    int ngroups = (count + 3) >> 2;
    for (int grp = blockIdx.x; grp < ngroups; grp += gridDim.x) {
        int node = grp * 4 + wv;
        if (node < count) {
            int n = base + node;
            xs[wv][lane] = x[n * D + lane];
            float s0 = 0.f, s1 = 0.f;
            #pragma unroll
            for (int d = 0; d < D; ++d) {
                float xv = xs[wv][d];
                s0 = fmaf(xv, Ws[d][lane],      s0);
                s1 = fmaf(xv, Ws[d][lane + 64], s1);
            }
            float m = fmaxf(s0, s1);
            for (int off = 32; off; off >>= 1) m = fmaxf(m, __shfl_xor(m, off));
            float e0 = __expf(s0 - m), e1 = __expf(s1 - m);
            float sm = e0 + e1;
            for (int off = 32; off; off >>= 1) sm += __shfl_xor(sm, off);
            float inv = 1.f / sm;
            ps[wv][lane]      = e0 * inv;
            ps[wv][lane + 64] = e1 * inv;
            float out = 0.f;
            #pragma unroll
            for (int k = 0; k < KDIM; ++k) out = fmaf(ps[wv][k], Ws[lane][k], out);
            intl[n * D + lane] = out;
            float ss = out * out;
            for (int off = 32; off; off >>= 1) ss += __shfl_xor(ss, off);
            if (lane == 0) rn_i[n] = 1.f / fmaxf(sqrtf(ss), EPSF);
        }
    }
}

// wave-per-row fused adaptive pass: alphas + unnormalized gaa/iaa SPMM in ONE
// edge loop (normalize by 1/rowsum afterwards), then combine + acc update.
__global__ __launch_bounds__(256) void k_fused(const int* __restrict__ row_off,
                                               const int* __restrict__ csr_t,
                                               const float* __restrict__ gnn,
                                               const float* __restrict__ intl,
                                               const float* __restrict__ rn_g,
                                               const float* __restrict__ rn_i,
                                               const float* __restrict__ x_in,
                                               float* __restrict__ x_out,
                                               float* __restrict__ acc) {
    int wid  = (blockIdx.x * blockDim.x + threadIdx.x) >> 6;
    int lane = threadIdx.x & 63;
    if (wid >= NN) return;
    int s = row_off[wid], eend = row_off[wid + 1];
    float hg = gnn[wid * D + lane] * rn_g[wid];
    float hi = intl[wid * D + lane] * rn_i[wid];
    float sum_g = 0.f, sum_i = 0.f, accg = 0.f, acci = 0.f;
    for (int e = s; e < eend; ++e) {
        int t = csr_t[e];
        float gv = gnn[t * D + lane];
        float iv = intl[t * D + lane];
        float xv = x_in[t * D + lane];
        float pg = hg * gv, pi = hi * iv;
        for (int off = 32; off; off >>= 1) {
            pg += __shfl_xor(pg, off);
            pi += __shfl_xor(pi, off);
        }
        float ag = fmaf(pg * rn_g[t], 0.5f, 0.5f);
        float ai = fmaf(pi * rn_i[t], 0.5f, 0.5f);
        sum_g += ag; sum_i += ai;
        accg = fmaf(ag, xv, accg);
        acci = fmaf(ai, xv, acci);
    }
    float invg = sum_g > 0.f ? 1.f / sum_g : 0.f;
    float invi = sum_i > 0.f ? 1.f / sum_i : 0.f;
    float xn = gnn[wid * D + lane] + intl[wid * D + lane]
             + invg * accg + invi * acci + x_in[wid * D + lane];
    x_out[wid * D + lane] = xn;
    acc[wid * D + lane]  += xn;
}

// ---------------- launch ----------------

extern "C" void kernel_launch(void* const* d_in, const int* in_sizes, int n_in,
                              void* d_out, int out_size, void* d_ws, size_t ws_size,
                              hipStream_t stream) {
    const float* emb   = (const float*)d_in[0];
    const float* Wu    = (const float*)d_in[1];
    const float* Wi    = (const float*)d_in[2];
    const int*   all_h = (const int*)d_in[3];
    const int*   all_t = (const int*)d_in[4];
    float*       acc   = (float*)d_out;

    char*  base = (char*)d_ws;
    size_t off  = 0;
    auto take = [&](size_t bytes) -> char* {
        char* r = base + off;
        off = (off + bytes + 255) & ~(size_t)255;
        return r;
    };
    int*   deg     = (int*)  take((size_t)NN * 4);
    int*   row_off = (int*)  take((size_t)(NN + 1) * 4);
    int*   row_cur = (int*)  take((size_t)NN * 4);
    int*   blk     = (int*)  take(1024 * 4);
    float* d_inv   = (float*)take((size_t)NN * 4);
    float* rn_g    = (float*)take((size_t)NN * 4);
    float* rn_i    = (float*)take((size_t)NN * 4);
    int*   csr_t   = (int*)  take((size_t)NE * 4);
    float* csr_gv  = (float*)take((size_t)NE * 4);
    float* x0      = (float*)take((size_t)NN * D * 4);
    float* x1      = (float*)take((size_t)NN * D * 4);
    float* gnn     = (float*)take((size_t)NN * D * 4);
    float* intl    = (float*)take((size_t)NN * D * 4);
    (void)ws_size; (void)in_sizes; (void)n_in; (void)out_size;

    hipMemsetAsync(deg, 0, (size_t)NN * 4, stream);
    hipMemsetAsync(row_cur, 0, (size_t)NN * 4, stream);

    const int EB = (NE + 255) / 256;
    k_deg<<<EB, 256, 0, stream>>>(all_h, deg);
    k_blk_sum<<<NB, 256, 0, stream>>>(deg, blk);
    k_scan_blk<<<1, 1024, 0, stream>>>(blk);
    k_scan_final<<<NB, 256, 0, stream>>>(deg, blk, row_off, d_inv);
    k_scatter<<<EB, 256, 0, stream>>>(all_h, all_t, row_off, row_cur, d_inv, csr_t, csr_gv);

    k_init<<<(NN * D / 4 + 255) / 256, 256, 0, stream>>>(emb, x0, acc);

    float* xin  = x0;
    float* xout = x1;
    const int RB = (NN + 3) / 4;   // wave-per-row blocks (4 waves/block)
    for (int l = 0; l < 3; ++l) {
        k_gnn<<<RB, 256, 0, stream>>>(row_off, csr_t, csr_gv, xin, gnn, rn_g);
        k_intent<<<1024, 256, 0, stream>>>(xin, Wu, intl, rn_i, 0, N_USERS);
        k_intent<<<512, 256, 0, stream>>>(xin, Wi, intl, rn_i, N_USERS, N_ITEMS);
        k_fused<<<RB, 256, 0, stream>>>(row_off, csr_t, gnn, intl, rn_g, rn_i,
                                        xin, xout, acc);
        float* tmp = xin; xin = xout; xout = tmp;
    }
}

// Round 2
// 1639.861 us; speedup vs baseline: 1.2227x; 1.2227x over previous
//
#include <hip/hip_runtime.h>

#define N_USERS 90000
#define N_ITEMS 60000
#define NN      (N_USERS + N_ITEMS)   // 150000
#define D       64
#define KDIM    128
#define NE      1600000
#define EPSF    1e-12f
#define NB      ((NN + 255) / 256)    // blocks for scans

// ---------------- helpers ----------------

__device__ inline unsigned short bf16_rne(float f) {
    unsigned u = __float_as_uint(f);
    unsigned r = (u + 0x7fffu + ((u >> 16) & 1u)) >> 16;
    return (unsigned short)r;
}
__device__ inline unsigned pack_bf16x2(float lo, float hi) {
    return (unsigned)bf16_rne(lo) | ((unsigned)bf16_rne(hi) << 16);
}
__device__ inline float bf_lo(unsigned u) { return __uint_as_float(u << 16); }
__device__ inline float bf_hi(unsigned u) { return __uint_as_float(u & 0xffff0000u); }

// ---------------- CSR build ----------------

__global__ void k_deg(const int* __restrict__ h, int* __restrict__ deg) {
    int e = blockIdx.x * blockDim.x + threadIdx.x;
    if (e < NE) atomicAdd(&deg[h[e]], 1);
}

__global__ void k_blk_sum(const int* __restrict__ deg, int* __restrict__ blk) {
    __shared__ int s[4];
    int i = blockIdx.x * 256 + threadIdx.x;
    int v = (i < NN) ? deg[i] : 0;
    for (int off = 32; off; off >>= 1) v += __shfl_xor(v, off);
    if ((threadIdx.x & 63) == 0) s[threadIdx.x >> 6] = v;
    __syncthreads();
    if (threadIdx.x == 0) blk[blockIdx.x] = s[0] + s[1] + s[2] + s[3];
}

__global__ void k_scan_blk(int* __restrict__ blk) {
    __shared__ int s[1024];
    int t = threadIdx.x;
    int v = (t < NB) ? blk[t] : 0;
    s[t] = v;
    __syncthreads();
    for (int off = 1; off < 1024; off <<= 1) {
        int u = (t >= off) ? s[t - off] : 0;
        __syncthreads();
        s[t] += u;
        __syncthreads();
    }
    if (t < NB) blk[t] = (t == 0) ? 0 : s[t - 1];
}

__global__ void k_scan_final(const int* __restrict__ deg, const int* __restrict__ blk,
                             int* __restrict__ row_off, float* __restrict__ d_inv) {
    __shared__ int s[256];
    int t = threadIdx.x;
    int i = blockIdx.x * 256 + t;
    int v = (i < NN) ? deg[i] : 0;
    s[t] = v;
    __syncthreads();
    for (int off = 1; off < 256; off <<= 1) {
        int u = (t >= off) ? s[t - off] : 0;
        __syncthreads();
        s[t] += u;
        __syncthreads();
    }
    if (i < NN) {
        row_off[i] = blk[blockIdx.x] + s[t] - v;
        d_inv[i]   = (v > 0) ? rsqrtf((float)v) : 0.f;
    }
    if (i == 0) row_off[NN] = NE;
}

__global__ void k_scatter(const int* __restrict__ h, const int* __restrict__ t,
                          const int* __restrict__ row_off, int* __restrict__ row_cur,
                          const float* __restrict__ d_inv,
                          int* __restrict__ csr_t, float* __restrict__ csr_gv) {
    int e = blockIdx.x * blockDim.x + threadIdx.x;
    if (e >= NE) return;
    int hh = h[e], tt = t[e];
    int slot = row_off[hh] + atomicAdd(&row_cur[hh], 1);
    csr_t[slot]  = tt;
    csr_gv[slot] = d_inv[hh] * d_inv[tt];
}

// ---------------- init ----------------

__global__ void k_init(const float* __restrict__ emb, float* __restrict__ xt,
                       float* __restrict__ acc) {
    int i = blockIdx.x * blockDim.x + threadIdx.x;   // over NN*D/4 float4s
    float4 v = ((const float4*)emb)[i];
    ((float4*)xt)[i]  = v;
    ((float4*)acc)[i] = v;
}

// ---------------- k_gnn: SPMM + norm + pack ----------------
// pk row (512B = 128 dwords): [0..31]=gn-hat bf16x2, [32..63]=in-hat bf16x2,
//                             [64..127]=x f32
__global__ __launch_bounds__(256) void k_gnn(const int* __restrict__ row_off,
                                             const int* __restrict__ csr_t,
                                             const float* __restrict__ csr_gv,
                                             const float* __restrict__ xt,
                                             unsigned* __restrict__ pk,
                                             float* __restrict__ base) {
    int wid  = (blockIdx.x * blockDim.x + threadIdx.x) >> 6;
    int lane = threadIdx.x & 63;
    if (wid >= NN) return;
    int e = row_off[wid], eend = row_off[wid + 1];
    float a = 0.f;
    for (; e + 1 < eend; e += 2) {
        int   t0 = csr_t[e],  t1 = csr_t[e + 1];
        float g0 = csr_gv[e], g1 = csr_gv[e + 1];
        a = fmaf(g0, xt[(size_t)t0 * D + lane], a);
        a = fmaf(g1, xt[(size_t)t1 * D + lane], a);
    }
    if (e < eend) a = fmaf(csr_gv[e], xt[(size_t)csr_t[e] * D + lane], a);
    float ss = a * a;
    for (int off = 32; off; off >>= 1) ss += __shfl_xor(ss, off);
    float nrm = fmaxf(sqrtf(ss), EPSF);
    float gn  = a * (1.0f / nrm);
    float oth = __shfl_xor(gn, 1);
    unsigned* pr = pk + (size_t)wid * 128;
    if (!(lane & 1)) pr[lane >> 1] = pack_bf16x2(gn, oth);
    float xr = xt[(size_t)wid * D + lane];
    ((float*)pr)[64 + lane] = xr;           // pk.x copy
    base[(size_t)wid * D + lane] = a + xr;  // gnn + x
}

// ---------------- k_int_tile: softmax(x@W)@W^T, 64-node tile ----------------
// dynamic LDS: Ws[64][128] | Wt[128][64] | sh2 = union(xs_t[64][68], ps[64][132])
#define INT_SMEM_FLOATS (8192 + 8192 + 8448)
#define INT_SMEM_BYTES  (INT_SMEM_FLOATS * 4)

__global__ __launch_bounds__(256) void k_int_tile(const float* __restrict__ xt,
                                                  const float* __restrict__ W,
                                                  unsigned* __restrict__ pk,
                                                  float* __restrict__ base,
                                                  int bse, int count) {
    extern __shared__ float smem[];
    float* Ws  = smem;             // [64][128]
    float* Wt  = smem + 8192;      // [128][64]
    float* sh2 = smem + 16384;     // xs_t [64][68] then ps [64][132]

    int tid = threadIdx.x;
    // stage W (row-major) and W^T
    for (int i = tid; i < D * KDIM; i += 256) Ws[i] = W[i];
    for (int i = tid; i < D * KDIM; i += 256) {
        int d = i & 63, k = i >> 6;
        Wt[k * 64 + d] = W[d * KDIM + k];
    }

    int n0 = blockIdx.x * 64;
    // stage x tile transposed: xs_t[d][nl]
    __syncthreads();
    for (int i = tid; i < 64 * 64; i += 256) {
        int nl = i >> 6, d = i & 63;
        int n  = n0 + nl;
        float v = (n < count) ? xt[(size_t)(bse + n) * D + d] : 0.f;
        sh2[d * 68 + nl] = v;
    }
    __syncthreads();

    int wv = tid >> 6;
    int la = tid & 63;
    int ag = la >> 4;        // node sub-group 0..3
    int bg = la & 15;        // k sub-group 0..15
    int nbase = wv * 16 + ag * 4;   // first of 4 local nodes

    // phase 1: logits. lane owns nodes nbase+i (i<4), k = 32*j + 2*bg + e
    float acc[4][4][2];
    #pragma unroll
    for (int i = 0; i < 4; ++i)
        #pragma unroll
        for (int j = 0; j < 4; ++j) { acc[i][j][0] = 0.f; acc[i][j][1] = 0.f; }

    #pragma unroll 4
    for (int d = 0; d < 64; ++d) {
        float4 xv = *(const float4*)&sh2[d * 68 + nbase];
        float2 w0 = *(const float2*)&Ws[d * KDIM +  0 + 2 * bg];
        float2 w1 = *(const float2*)&Ws[d * KDIM + 32 + 2 * bg];
        float2 w2 = *(const float2*)&Ws[d * KDIM + 64 + 2 * bg];
        float2 w3 = *(const float2*)&Ws[d * KDIM + 96 + 2 * bg];
        float xx[4] = {xv.x, xv.y, xv.z, xv.w};
        float wl[4] = {w0.x, w1.x, w2.x, w3.x};
        float wh[4] = {w0.y, w1.y, w2.y, w3.y};
        #pragma unroll
        for (int i = 0; i < 4; ++i)
            #pragma unroll
            for (int j = 0; j < 4; ++j) {
                acc[i][j][0] = fmaf(xx[i], wl[j], acc[i][j][0]);
                acc[i][j][1] = fmaf(xx[i], wh[j], acc[i][j][1]);
            }
    }

    // softmax over k per node (reduce over bg lanes: masks 1,2,4,8)
    float p[4][4][2];
    float inv_s[4];
    #pragma unroll
    for (int i = 0; i < 4; ++i) {
        float m = acc[i][0][0];
        #pragma unroll
        for (int j = 0; j < 4; ++j) {
            m = fmaxf(m, acc[i][j][0]);
            m = fmaxf(m, acc[i][j][1]);
        }
        m = fmaxf(m, __shfl_xor(m, 1));
        m = fmaxf(m, __shfl_xor(m, 2));
        m = fmaxf(m, __shfl_xor(m, 4));
        m = fmaxf(m, __shfl_xor(m, 8));
        float sm = 0.f;
        #pragma unroll
        for (int j = 0; j < 4; ++j) {
            p[i][j][0] = __expf(acc[i][j][0] - m);
            p[i][j][1] = __expf(acc[i][j][1] - m);
            sm += p[i][j][0] + p[i][j][1];
        }
        sm += __shfl_xor(sm, 1);
        sm += __shfl_xor(sm, 2);
        sm += __shfl_xor(sm, 4);
        sm += __shfl_xor(sm, 8);
        inv_s[i] = 1.f / sm;
    }

    __syncthreads();   // all phase-1 xs_t reads done before ps overwrites sh2

    #pragma unroll
    for (int i = 0; i < 4; ++i) {
        float is = inv_s[i];
        #pragma unroll
        for (int j = 0; j < 4; ++j) {
            float2 pv = make_float2(p[i][j][0] * is, p[i][j][1] * is);
            *(float2*)&sh2[(nbase + i) * 132 + 32 * j + 2 * bg] = pv;
        }
    }
    __syncthreads();

    // phase 2: out[n][d] = sum_k p[n][k] * W[d][k]; lane owns 4n x 4d (d=4*bg+r)
    float o[4][4];
    #pragma unroll
    for (int i = 0; i < 4; ++i)
        #pragma unroll
        for (int r = 0; r < 4; ++r) o[i][r] = 0.f;

    int dbase = bg * 4;
    for (int k = 0; k < KDIM; k += 4) {
        float4 P[4];
        #pragma unroll
        for (int i = 0; i < 4; ++i)
            P[i] = *(const float4*)&sh2[(nbase + i) * 132 + k];
        float4 Wv[4];
        #pragma unroll
        for (int c = 0; c < 4; ++c)
            Wv[c] = *(const float4*)&Wt[(k + c) * 64 + dbase];
        #pragma unroll
        for (int c = 0; c < 4; ++c) {
            float wr[4] = {Wv[c].x, Wv[c].y, Wv[c].z, Wv[c].w};
            float pc[4] = {((const float*)&P[0])[c], ((const float*)&P[1])[c],
                           ((const float*)&P[2])[c], ((const float*)&P[3])[c]};
            #pragma unroll
            for (int i = 0; i < 4; ++i)
                #pragma unroll
                for (int r = 0; r < 4; ++r)
                    o[i][r] = fmaf(pc[i], wr[r], o[i][r]);
        }
    }

    // epilogue: norm over d (reduce over bg lanes), base += intl, pk.in-hat
    #pragma unroll
    for (int i = 0; i < 4; ++i) {
        int n = n0 + wv * 16 + ag * 4 + i;
        float ss = o[i][0]*o[i][0] + o[i][1]*o[i][1] + o[i][2]*o[i][2] + o[i][3]*o[i][3];
        ss += __shfl_xor(ss, 1);
        ss += __shfl_xor(ss, 2);
        ss += __shfl_xor(ss, 4);
        ss += __shfl_xor(ss, 8);
        if (n < count) {
            size_t g = (size_t)(bse + n);
            float invn = 1.0f / fmaxf(sqrtf(ss), EPSF);
            float4* bp = (float4*)&base[g * D + dbase];
            float4 bv = *bp;
            bv.x += o[i][0]; bv.y += o[i][1]; bv.z += o[i][2]; bv.w += o[i][3];
            *bp = bv;
            unsigned d0 = pack_bf16x2(o[i][0] * invn, o[i][1] * invn);
            unsigned d1 = pack_bf16x2(o[i][2] * invn, o[i][3] * invn);
            unsigned* pr = pk + g * 128 + 32;   // in-hat region
            ((uint2*)pr)[bg] = make_uint2(d0, d1);
        }
    }
}

// ---------------- k_fused: adaptive alphas + gaa/iaa + combine ----------------
// two edges per wave: lanes 0-31 -> edge e, lanes 32-63 -> edge e+1, 2 feats/lane
__global__ __launch_bounds__(256) void k_fused(const int* __restrict__ row_off,
                                               const int* __restrict__ csr_t,
                                               const unsigned* __restrict__ pk,
                                               const float* __restrict__ base,
                                               float* __restrict__ xt_out,
                                               float* __restrict__ acc) {
    int wid  = (blockIdx.x * blockDim.x + threadIdx.x) >> 6;
    int lane = threadIdx.x & 63;
    if (wid >= NN) return;
    int half = lane >> 5;
    int l32  = lane & 31;

    const unsigned* ph = pk + (size_t)wid * 128;
    unsigned ugh = ph[l32];
    unsigned uih = ph[32 + l32];
    float hgx = bf_lo(ugh), hgy = bf_hi(ugh);
    float hix = bf_lo(uih), hiy = bf_hi(uih);

    int s = row_off[wid], eend = row_off[wid + 1];
    float sg = 0.f, si = 0.f;
    float agx = 0.f, agy = 0.f, aix = 0.f, aiy = 0.f;

    for (int e = s; e < eend; e += 2) {
        int ee = e + half;
        int t  = csr_t[min(ee, eend - 1)];
        const unsigned* pr = pk + (size_t)t * 128;
        unsigned ug = pr[l32];
        unsigned ui = pr[32 + l32];
        float2 xv   = ((const float2*)(pr + 64))[l32];
        float pg = fmaf(hgx, bf_lo(ug), hgy * bf_hi(ug));
        float pi = fmaf(hix, bf_lo(ui), hiy * bf_hi(ui));
        pg += __shfl_xor(pg, 1);  pi += __shfl_xor(pi, 1);
        pg += __shfl_xor(pg, 2);  pi += __shfl_xor(pi, 2);
        pg += __shfl_xor(pg, 4);  pi += __shfl_xor(pi, 4);
        pg += __shfl_xor(pg, 8);  pi += __shfl_xor(pi, 8);
        pg += __shfl_xor(pg, 16); pi += __shfl_xor(pi, 16);
        float ag = fmaf(pg, 0.5f, 0.5f);
        float ai = fmaf(pi, 0.5f, 0.5f);
        if (ee >= eend) { ag = 0.f; ai = 0.f; }
        sg += ag; si += ai;
        agx = fmaf(ag, xv.x, agx); agy = fmaf(ag, xv.y, agy);
        aix = fmaf(ai, xv.x, aix); aiy = fmaf(ai, xv.y, aiy);
    }

    sg  += __shfl_xor(sg, 32);  si  += __shfl_xor(si, 32);
    agx += __shfl_xor(agx, 32); agy += __shfl_xor(agy, 32);
    aix += __shfl_xor(aix, 32); aiy += __shfl_xor(aiy, 32);

    if (half == 0) {
        float invg = sg > 0.f ? 1.f / sg : 0.f;
        float invi = si > 0.f ? 1.f / si : 0.f;
        size_t idx = (size_t)wid * 32 + l32;
        float2 b = ((const float2*)base)[idx];
        float nx = b.x + invg * agx + invi * aix;
        float ny = b.y + invg * agy + invi * aiy;
        ((float2*)xt_out)[idx] = make_float2(nx, ny);
        float2 a = ((float2*)acc)[idx];
        a.x += nx; a.y += ny;
        ((float2*)acc)[idx] = a;
    }
}

// ---------------- launch ----------------

extern "C" void kernel_launch(void* const* d_in, const int* in_sizes, int n_in,
                              void* d_out, int out_size, void* d_ws, size_t ws_size,
                              hipStream_t stream) {
    const float* emb   = (const float*)d_in[0];
    const float* Wu    = (const float*)d_in[1];
    const float* Wi    = (const float*)d_in[2];
    const int*   all_h = (const int*)d_in[3];
    const int*   all_t = (const int*)d_in[4];
    float*       acc   = (float*)d_out;

    char*  bp  = (char*)d_ws;
    size_t off = 0;
    auto take = [&](size_t bytes) -> char* {
        char* r = bp + off;
        off = (off + bytes + 255) & ~(size_t)255;
        return r;
    };
    int*      deg     = (int*)     take((size_t)NN * 4);
    int*      row_off = (int*)     take((size_t)(NN + 1) * 4);
    int*      row_cur = (int*)     take((size_t)NN * 4);
    int*      blk     = (int*)     take(1024 * 4);
    float*    d_inv   = (float*)   take((size_t)NN * 4);
    int*      csr_t   = (int*)     take((size_t)NE * 4);
    float*    csr_gv  = (float*)   take((size_t)NE * 4);
    unsigned* pk      = (unsigned*)take((size_t)NN * 512);
    float*    xt      = (float*)   take((size_t)NN * D * 4);
    float*    base    = (float*)   take((size_t)NN * D * 4);
    (void)ws_size; (void)in_sizes; (void)n_in; (void)out_size;

    hipFuncSetAttribute((const void*)k_int_tile,
                        hipFuncAttributeMaxDynamicSharedMemorySize, INT_SMEM_BYTES);

    hipMemsetAsync(deg, 0, (size_t)NN * 4, stream);
    hipMemsetAsync(row_cur, 0, (size_t)NN * 4, stream);

    const int EB = (NE + 255) / 256;
    k_deg<<<EB, 256, 0, stream>>>(all_h, deg);
    k_blk_sum<<<NB, 256, 0, stream>>>(deg, blk);
    k_scan_blk<<<1, 1024, 0, stream>>>(blk);
    k_scan_final<<<NB, 256, 0, stream>>>(deg, blk, row_off, d_inv);
    k_scatter<<<EB, 256, 0, stream>>>(all_h, all_t, row_off, row_cur, d_inv, csr_t, csr_gv);

    k_init<<<(NN * D / 4 + 255) / 256, 256, 0, stream>>>(emb, xt, acc);

    const int RB = (NN + 3) / 4;            // 4 waves/block
    const int TU = (N_USERS + 63) / 64;     // user tiles
    const int TI = (N_ITEMS + 63) / 64;     // item tiles
    for (int l = 0; l < 3; ++l) {
        k_gnn<<<RB, 256, 0, stream>>>(row_off, csr_t, csr_gv, xt, pk, base);
        k_int_tile<<<TU, 256, INT_SMEM_BYTES, stream>>>(xt, Wu, pk, base, 0, N_USERS);
        k_int_tile<<<TI, 256, INT_SMEM_BYTES, stream>>>(xt, Wi, pk, base, N_USERS, N_ITEMS);
        k_fused<<<RB, 256, 0, stream>>>(row_off, csr_t, pk, base, xt, acc);
    }
}

// Round 3
// 1427.248 us; speedup vs baseline: 1.4048x; 1.1490x over previous
//
#include <hip/hip_runtime.h>

#define N_USERS 90000
#define N_ITEMS 60000
#define NN      (N_USERS + N_ITEMS)   // 150000
#define D       64
#define KDIM    128
#define NE      1600000
#define EPSF    1e-12f
#define NB      ((NN + 255) / 256)
#define ROWD    96                    // pk row = 96 dwords = 384B
#define TU      ((N_USERS + 63) / 64) // 1407
#define TI      ((N_ITEMS + 63) / 64) // 938

// ---------------- helpers ----------------

__device__ inline unsigned short bf16_rne(float f) {
    unsigned u = __float_as_uint(f);
    unsigned r = (u + 0x7fffu + ((u >> 16) & 1u)) >> 16;
    return (unsigned short)r;
}
__device__ inline unsigned pack_bf16x2(float lo, float hi) {
    return (unsigned)bf16_rne(lo) | ((unsigned)bf16_rne(hi) << 16);
}
__device__ inline float bf_lo(unsigned u) { return __uint_as_float(u << 16); }
__device__ inline float bf_hi(unsigned u) { return __uint_as_float(u & 0xffff0000u); }

// ---------------- CSR build ----------------

__global__ void k_deg(const int* __restrict__ h, int* __restrict__ deg) {
    int e = blockIdx.x * blockDim.x + threadIdx.x;
    if (e < NE) atomicAdd(&deg[h[e]], 1);
}

__global__ void k_blk_sum(const int* __restrict__ deg, int* __restrict__ blk) {
    __shared__ int s[4];
    int i = blockIdx.x * 256 + threadIdx.x;
    int v = (i < NN) ? deg[i] : 0;
    for (int off = 32; off; off >>= 1) v += __shfl_xor(v, off);
    if ((threadIdx.x & 63) == 0) s[threadIdx.x >> 6] = v;
    __syncthreads();
    if (threadIdx.x == 0) blk[blockIdx.x] = s[0] + s[1] + s[2] + s[3];
}

__global__ void k_scan_blk(int* __restrict__ blk) {
    __shared__ int s[1024];
    int t = threadIdx.x;
    int v = (t < NB) ? blk[t] : 0;
    s[t] = v;
    __syncthreads();
    for (int off = 1; off < 1024; off <<= 1) {
        int u = (t >= off) ? s[t - off] : 0;
        __syncthreads();
        s[t] += u;
        __syncthreads();
    }
    if (t < NB) blk[t] = (t == 0) ? 0 : s[t - 1];
}

__global__ void k_scan_final(const int* __restrict__ deg, const int* __restrict__ blk,
                             int* __restrict__ row_off, float* __restrict__ d_inv) {
    __shared__ int s[256];
    int t = threadIdx.x;
    int i = blockIdx.x * 256 + t;
    int v = (i < NN) ? deg[i] : 0;
    s[t] = v;
    __syncthreads();
    for (int off = 1; off < 256; off <<= 1) {
        int u = (t >= off) ? s[t - off] : 0;
        __syncthreads();
        s[t] += u;
        __syncthreads();
    }
    if (i < NN) {
        row_off[i] = blk[blockIdx.x] + s[t] - v;
        d_inv[i]   = (v > 0) ? rsqrtf((float)v) : 0.f;
    }
    if (i == 0) row_off[NN] = NE;
}

__global__ void k_scatter(const int* __restrict__ h, const int* __restrict__ t,
                          const int* __restrict__ row_off, int* __restrict__ row_cur,
                          const float* __restrict__ d_inv,
                          int2* __restrict__ csr) {
    int e = blockIdx.x * blockDim.x + threadIdx.x;
    if (e >= NE) return;
    int hh = h[e], tt = t[e];
    int slot = row_off[hh] + atomicAdd(&row_cur[hh], 1);
    csr[slot] = make_int2(tt, __float_as_int(d_inv[hh] * d_inv[tt]));
}

// ---------------- init ----------------
// thread per float2 (2 feats): xt, acc f32; pkA.x bf16
__global__ void k_init(const float* __restrict__ emb, float* __restrict__ xt,
                       float* __restrict__ acc, unsigned* __restrict__ pkA) {
    int i = blockIdx.x * blockDim.x + threadIdx.x;   // < NN*32
    if (i >= NN * 32) return;
    float2 v = ((const float2*)emb)[i];
    ((float2*)xt)[i]  = v;
    ((float2*)acc)[i] = v;
    pkA[(size_t)(i >> 5) * ROWD + 64 + (i & 31)] = pack_bf16x2(v.x, v.y);
}

// ---------------- k_gnn: SPMM(bf16 gather) + norm + pack ----------------
// wave = 2 edges (32-lane halves), lane l32 owns feats {2*l32, 2*l32+1}
__global__ __launch_bounds__(256) void k_gnn(const int* __restrict__ row_off,
                                             const int2* __restrict__ csr,
                                             unsigned* __restrict__ pk,
                                             const float* __restrict__ xt,
                                             float* __restrict__ base_) {
    int wid  = (blockIdx.x * blockDim.x + threadIdx.x) >> 6;
    int lane = threadIdx.x & 63;
    if (wid >= NN) return;
    int half = lane >> 5, l32 = lane & 31;
    int s = row_off[wid], eend = row_off[wid + 1];
    float ax = 0.f, ay = 0.f;
    int e = s;
    for (; e + 3 < eend; e += 4) {
        int2 tg0 = csr[e + half];
        int2 tg1 = csr[e + 2 + half];
        unsigned x0 = pk[(size_t)tg0.x * ROWD + 64 + l32];
        unsigned x1 = pk[(size_t)tg1.x * ROWD + 64 + l32];
        float g0 = __int_as_float(tg0.y), g1 = __int_as_float(tg1.y);
        ax = fmaf(g0, bf_lo(x0), ax); ay = fmaf(g0, bf_hi(x0), ay);
        ax = fmaf(g1, bf_lo(x1), ax); ay = fmaf(g1, bf_hi(x1), ay);
    }
    for (; e < eend; e += 2) {
        int ee = e + half;
        int2 tg = csr[min(ee, eend - 1)];
        float gv = (ee < eend) ? __int_as_float(tg.y) : 0.f;
        unsigned xw = pk[(size_t)tg.x * ROWD + 64 + l32];
        ax = fmaf(gv, bf_lo(xw), ax); ay = fmaf(gv, bf_hi(xw), ay);
    }
    ax += __shfl_xor(ax, 32); ay += __shfl_xor(ay, 32);
    float ss = fmaf(ax, ax, ay * ay);
    #pragma unroll
    for (int m = 1; m <= 16; m <<= 1) ss += __shfl_xor(ss, m);
    float inv = 1.f / fmaxf(sqrtf(ss), EPSF);
    if (half == 0) {
        pk[(size_t)wid * ROWD + l32] = pack_bf16x2(ax * inv, ay * inv);
        size_t idx = (size_t)wid * 32 + l32;
        float2 xr = ((const float2*)xt)[idx];
        ((float2*)base_)[idx] = make_float2(ax + xr.x, ay + xr.y);
    }
}

// ---------------- k_int: softmax(x@W)@W^T, 64-node tile, users+items ----------
#define INT_SMEM_FLOATS (8192 + 8192 + 8448)
#define INT_SMEM_BYTES  (INT_SMEM_FLOATS * 4)

__global__ __launch_bounds__(256) void k_int(const float* __restrict__ xt,
                                             const float* __restrict__ Wu,
                                             const float* __restrict__ Wi,
                                             unsigned* __restrict__ pk,
                                             float* __restrict__ base_) {
    extern __shared__ float smem[];
    float* Ws  = smem;             // [64][128]
    float* Wt  = smem + 8192;      // [128][64]
    float* sh2 = smem + 16384;     // xs_t [64][68] then ps [64][132]

    const float* W;
    int bse, count, n0;
    if (blockIdx.x < TU) { W = Wu; bse = 0;       count = N_USERS; n0 = blockIdx.x * 64; }
    else                 { W = Wi; bse = N_USERS; count = N_ITEMS; n0 = (blockIdx.x - TU) * 64; }

    int tid = threadIdx.x;
    for (int i = tid; i < D * KDIM; i += 256) Ws[i] = W[i];
    for (int i = tid; i < D * KDIM; i += 256) {
        int d = i & 63, k = i >> 6;
        Wt[k * 64 + d] = W[d * KDIM + k];
    }
    __syncthreads();
    for (int i = tid; i < 64 * 64; i += 256) {
        int nl = i >> 6, d = i & 63;
        int n  = n0 + nl;
        float v = (n < count) ? xt[(size_t)(bse + n) * D + d] : 0.f;
        sh2[d * 68 + nl] = v;
    }
    __syncthreads();

    int wv = tid >> 6;
    int la = tid & 63;
    int ag = la >> 4;
    int bg = la & 15;
    int nbase = wv * 16 + ag * 4;

    float acc[4][4][2];
    #pragma unroll
    for (int i = 0; i < 4; ++i)
        #pragma unroll
        for (int j = 0; j < 4; ++j) { acc[i][j][0] = 0.f; acc[i][j][1] = 0.f; }

    #pragma unroll 4
    for (int d = 0; d < 64; ++d) {
        float4 xv = *(const float4*)&sh2[d * 68 + nbase];
        float2 w0 = *(const float2*)&Ws[d * KDIM +  0 + 2 * bg];
        float2 w1 = *(const float2*)&Ws[d * KDIM + 32 + 2 * bg];
        float2 w2 = *(const float2*)&Ws[d * KDIM + 64 + 2 * bg];
        float2 w3 = *(const float2*)&Ws[d * KDIM + 96 + 2 * bg];
        float xx[4] = {xv.x, xv.y, xv.z, xv.w};
        float wl[4] = {w0.x, w1.x, w2.x, w3.x};
        float wh[4] = {w0.y, w1.y, w2.y, w3.y};
        #pragma unroll
        for (int i = 0; i < 4; ++i)
            #pragma unroll
            for (int j = 0; j < 4; ++j) {
                acc[i][j][0] = fmaf(xx[i], wl[j], acc[i][j][0]);
                acc[i][j][1] = fmaf(xx[i], wh[j], acc[i][j][1]);
            }
    }

    float p[4][4][2];
    float inv_s[4];
    #pragma unroll
    for (int i = 0; i < 4; ++i) {
        float m = acc[i][0][0];
        #pragma unroll
        for (int j = 0; j < 4; ++j) {
            m = fmaxf(m, acc[i][j][0]);
            m = fmaxf(m, acc[i][j][1]);
        }
        m = fmaxf(m, __shfl_xor(m, 1));
        m = fmaxf(m, __shfl_xor(m, 2));
        m = fmaxf(m, __shfl_xor(m, 4));
        m = fmaxf(m, __shfl_xor(m, 8));
        float sm = 0.f;
        #pragma unroll
        for (int j = 0; j < 4; ++j) {
            p[i][j][0] = __expf(acc[i][j][0] - m);
            p[i][j][1] = __expf(acc[i][j][1] - m);
            sm += p[i][j][0] + p[i][j][1];
        }
        sm += __shfl_xor(sm, 1);
        sm += __shfl_xor(sm, 2);
        sm += __shfl_xor(sm, 4);
        sm += __shfl_xor(sm, 8);
        inv_s[i] = 1.f / sm;
    }

    __syncthreads();
    #pragma unroll
    for (int i = 0; i < 4; ++i) {
        float is = inv_s[i];
        #pragma unroll
        for (int j = 0; j < 4; ++j) {
            float2 pv = make_float2(p[i][j][0] * is, p[i][j][1] * is);
            *(float2*)&sh2[(nbase + i) * 132 + 32 * j + 2 * bg] = pv;
        }
    }
    __syncthreads();

    float o[4][4];
    #pragma unroll
    for (int i = 0; i < 4; ++i)
        #pragma unroll
        for (int r = 0; r < 4; ++r) o[i][r] = 0.f;

    int dbase = bg * 4;
    for (int k = 0; k < KDIM; k += 4) {
        float4 P[4];
        #pragma unroll
        for (int i = 0; i < 4; ++i)
            P[i] = *(const float4*)&sh2[(nbase + i) * 132 + k];
        float4 Wv[4];
        #pragma unroll
        for (int c = 0; c < 4; ++c)
            Wv[c] = *(const float4*)&Wt[(k + c) * 64 + dbase];
        #pragma unroll
        for (int c = 0; c < 4; ++c) {
            float wr[4] = {Wv[c].x, Wv[c].y, Wv[c].z, Wv[c].w};
            float pc[4] = {((const float*)&P[0])[c], ((const float*)&P[1])[c],
                           ((const float*)&P[2])[c], ((const float*)&P[3])[c]};
            #pragma unroll
            for (int i = 0; i < 4; ++i)
                #pragma unroll
                for (int r = 0; r < 4; ++r)
                    o[i][r] = fmaf(pc[i], wr[r], o[i][r]);
        }
    }

    #pragma unroll
    for (int i = 0; i < 4; ++i) {
        int n = n0 + wv * 16 + ag * 4 + i;
        float ss = o[i][0]*o[i][0] + o[i][1]*o[i][1] + o[i][2]*o[i][2] + o[i][3]*o[i][3];
        ss += __shfl_xor(ss, 1);
        ss += __shfl_xor(ss, 2);
        ss += __shfl_xor(ss, 4);
        ss += __shfl_xor(ss, 8);
        if (n < count) {
            size_t g = (size_t)(bse + n);
            float invn = 1.0f / fmaxf(sqrtf(ss), EPSF);
            float4* bp = (float4*)&base_[g * D + dbase];
            float4 bv = *bp;
            bv.x += o[i][0]; bv.y += o[i][1]; bv.z += o[i][2]; bv.w += o[i][3];
            *bp = bv;
            unsigned d0 = pack_bf16x2(o[i][0] * invn, o[i][1] * invn);
            unsigned d1 = pack_bf16x2(o[i][2] * invn, o[i][3] * invn);
            unsigned* pr = pk + g * ROWD + 32;
            ((uint2*)pr)[bg] = make_uint2(d0, d1);
        }
    }
}

// ---------------- k_fused: alphas + gaa/iaa + combine ----------------
__global__ __launch_bounds__(256) void k_fused(const int* __restrict__ row_off,
                                               const int2* __restrict__ csr,
                                               const unsigned* __restrict__ pk,
                                               const float* __restrict__ base_,
                                               float* __restrict__ xt,
                                               unsigned* __restrict__ pknext,
                                               float* __restrict__ acc) {
    int wid  = (blockIdx.x * blockDim.x + threadIdx.x) >> 6;
    int lane = threadIdx.x & 63;
    if (wid >= NN) return;
    int half = lane >> 5, l32 = lane & 31;

    const unsigned* ph = pk + (size_t)wid * ROWD;
    unsigned ugh = ph[l32];
    unsigned uih = ph[32 + l32];
    float hgx = bf_lo(ugh), hgy = bf_hi(ugh);
    float hix = bf_lo(uih), hiy = bf_hi(uih);

    int s = row_off[wid], eend = row_off[wid + 1];
    float sg = 0.f, si = 0.f;
    float agx = 0.f, agy = 0.f, aix = 0.f, aiy = 0.f;

    int e = s;
    for (; e + 3 < eend; e += 4) {
        int t0 = csr[e + half].x;
        int t1 = csr[e + 2 + half].x;
        const unsigned* p0 = pk + (size_t)t0 * ROWD;
        const unsigned* p1 = pk + (size_t)t1 * ROWD;
        unsigned ug0 = p0[l32], ui0 = p0[32 + l32], ux0 = p0[64 + l32];
        unsigned ug1 = p1[l32], ui1 = p1[32 + l32], ux1 = p1[64 + l32];
        float pg0 = fmaf(hgx, bf_lo(ug0), hgy * bf_hi(ug0));
        float pi0 = fmaf(hix, bf_lo(ui0), hiy * bf_hi(ui0));
        float pg1 = fmaf(hgx, bf_lo(ug1), hgy * bf_hi(ug1));
        float pi1 = fmaf(hix, bf_lo(ui1), hiy * bf_hi(ui1));
        #pragma unroll
        for (int m = 1; m <= 16; m <<= 1) {
            pg0 += __shfl_xor(pg0, m); pi0 += __shfl_xor(pi0, m);
            pg1 += __shfl_xor(pg1, m); pi1 += __shfl_xor(pi1, m);
        }
        float ag0 = fmaf(pg0, 0.5f, 0.5f), ai0 = fmaf(pi0, 0.5f, 0.5f);
        float ag1 = fmaf(pg1, 0.5f, 0.5f), ai1 = fmaf(pi1, 0.5f, 0.5f);
        sg += ag0 + ag1; si += ai0 + ai1;
        float x0l = bf_lo(ux0), x0h = bf_hi(ux0);
        float x1l = bf_lo(ux1), x1h = bf_hi(ux1);
        agx = fmaf(ag0, x0l, agx); agy = fmaf(ag0, x0h, agy);
        aix = fmaf(ai0, x0l, aix); aiy = fmaf(ai0, x0h, aiy);
        agx = fmaf(ag1, x1l, agx); agy = fmaf(ag1, x1h, agy);
        aix = fmaf(ai1, x1l, aix); aiy = fmaf(ai1, x1h, aiy);
    }
    for (; e < eend; e += 2) {
        int ee = e + half;
        int t  = csr[min(ee, eend - 1)].x;
        const unsigned* pr = pk + (size_t)t * ROWD;
        unsigned ug = pr[l32], ui = pr[32 + l32], ux = pr[64 + l32];
        float pg = fmaf(hgx, bf_lo(ug), hgy * bf_hi(ug));
        float pi = fmaf(hix, bf_lo(ui), hiy * bf_hi(ui));
        #pragma unroll
        for (int m = 1; m <= 16; m <<= 1) {
            pg += __shfl_xor(pg, m); pi += __shfl_xor(pi, m);
        }
        float ag = fmaf(pg, 0.5f, 0.5f);
        float ai = fmaf(pi, 0.5f, 0.5f);
        if (ee >= eend) { ag = 0.f; ai = 0.f; }
        sg += ag; si += ai;
        float xl = bf_lo(ux), xh = bf_hi(ux);
        agx = fmaf(ag, xl, agx); agy = fmaf(ag, xh, agy);
        aix = fmaf(ai, xl, aix); aiy = fmaf(ai, xh, aiy);
    }

    sg  += __shfl_xor(sg, 32);  si  += __shfl_xor(si, 32);
    agx += __shfl_xor(agx, 32); agy += __shfl_xor(agy, 32);
    aix += __shfl_xor(aix, 32); aiy += __shfl_xor(aiy, 32);

    if (half == 0) {
        float invg = sg > 0.f ? 1.f / sg : 0.f;
        float invi = si > 0.f ? 1.f / si : 0.f;
        size_t idx = (size_t)wid * 32 + l32;
        float2 b = ((const float2*)base_)[idx];
        float nx = b.x + invg * agx + invi * aix;
        float ny = b.y + invg * agy + invi * aiy;
        ((float2*)xt)[idx] = make_float2(nx, ny);
        pknext[(size_t)wid * ROWD + 64 + l32] = pack_bf16x2(nx, ny);
        float2 a = ((float2*)acc)[idx];
        a.x += nx; a.y += ny;
        ((float2*)acc)[idx] = a;
    }
}

// ---------------- launch ----------------

extern "C" void kernel_launch(void* const* d_in, const int* in_sizes, int n_in,
                              void* d_out, int out_size, void* d_ws, size_t ws_size,
                              hipStream_t stream) {
    const float* emb   = (const float*)d_in[0];
    const float* Wu    = (const float*)d_in[1];
    const float* Wi    = (const float*)d_in[2];
    const int*   all_h = (const int*)d_in[3];
    const int*   all_t = (const int*)d_in[4];
    float*       acc   = (float*)d_out;

    char*  bp  = (char*)d_ws;
    size_t off = 0;
    auto take = [&](size_t bytes) -> char* {
        char* r = bp + off;
        off = (off + bytes + 255) & ~(size_t)255;
        return r;
    };
    int*      deg     = (int*)     take((size_t)NN * 4);
    int*      row_off = (int*)     take((size_t)(NN + 1) * 4);
    int*      row_cur = (int*)     take((size_t)NN * 4);
    int*      blk     = (int*)     take(1024 * 4);
    float*    d_inv   = (float*)   take((size_t)NN * 4);
    int2*     csr     = (int2*)    take((size_t)NE * 8);
    unsigned* pkA     = (unsigned*)take((size_t)NN * ROWD * 4);
    unsigned* pkB     = (unsigned*)take((size_t)NN * ROWD * 4);
    float*    xt      = (float*)   take((size_t)NN * D * 4);
    float*    base_   = (float*)   take((size_t)NN * D * 4);
    (void)ws_size; (void)in_sizes; (void)n_in; (void)out_size;

    hipFuncSetAttribute((const void*)k_int,
                        hipFuncAttributeMaxDynamicSharedMemorySize, INT_SMEM_BYTES);

    hipMemsetAsync(deg, 0, (size_t)NN * 4, stream);
    hipMemsetAsync(row_cur, 0, (size_t)NN * 4, stream);

    const int EB = (NE + 255) / 256;
    k_deg<<<EB, 256, 0, stream>>>(all_h, deg);
    k_blk_sum<<<NB, 256, 0, stream>>>(deg, blk);
    k_scan_blk<<<1, 1024, 0, stream>>>(blk);
    k_scan_final<<<NB, 256, 0, stream>>>(deg, blk, row_off, d_inv);
    k_scatter<<<EB, 256, 0, stream>>>(all_h, all_t, row_off, row_cur, d_inv, csr);

    k_init<<<(NN * 32 + 255) / 256, 256, 0, stream>>>(emb, xt, acc, pkA);

    const int RB = (NN + 3) / 4;
    unsigned* cur = pkA;
    unsigned* nxt = pkB;
    for (int l = 0; l < 3; ++l) {
        k_gnn<<<RB, 256, 0, stream>>>(row_off, csr, cur, xt, base_);
        k_int<<<TU + TI, 256, INT_SMEM_BYTES, stream>>>(xt, Wu, Wi, cur, base_);
        k_fused<<<RB, 256, 0, stream>>>(row_off, csr, cur, base_, xt, nxt, acc);
        unsigned* tmp = cur; cur = nxt; nxt = tmp;
    }
}

// Round 4
// 1067.700 us; speedup vs baseline: 1.8779x; 1.3368x over previous
//
#include <hip/hip_runtime.h>

#define N_USERS 90000
#define N_ITEMS 60000
#define NN      (N_USERS + N_ITEMS)   // 150000
#define D       64
#define KDIM    128
#define NE      1600000
#define EPSF    1e-12f
#define NB      ((NN + 255) / 256)
#define ROWD    96                    // pk row = 96 dwords = 384B
#define TU      ((N_USERS + 63) / 64) // 1407
#define TI      ((N_ITEMS + 63) / 64) // 938

// ---------------- helpers ----------------

__device__ inline unsigned short bf16_rne(float f) {
    unsigned u = __float_as_uint(f);
    unsigned r = (u + 0x7fffu + ((u >> 16) & 1u)) >> 16;
    return (unsigned short)r;
}
__device__ inline unsigned pack_bf16x2(float lo, float hi) {
    return (unsigned)bf16_rne(lo) | ((unsigned)bf16_rne(hi) << 16);
}
__device__ inline float bf_lo(unsigned u) { return __uint_as_float(u << 16); }
__device__ inline float bf_hi(unsigned u) { return __uint_as_float(u & 0xffff0000u); }

// ---------------- CSR build ----------------

__global__ void k_deg(const int* __restrict__ h, int* __restrict__ deg) {
    int e = blockIdx.x * blockDim.x + threadIdx.x;
    if (e < NE) atomicAdd(&deg[h[e]], 1);
}

__global__ void k_blk_sum(const int* __restrict__ deg, int* __restrict__ blk) {
    __shared__ int s[4];
    int i = blockIdx.x * 256 + threadIdx.x;
    int v = (i < NN) ? deg[i] : 0;
    for (int off = 32; off; off >>= 1) v += __shfl_xor(v, off);
    if ((threadIdx.x & 63) == 0) s[threadIdx.x >> 6] = v;
    __syncthreads();
    if (threadIdx.x == 0) blk[blockIdx.x] = s[0] + s[1] + s[2] + s[3];
}

__global__ void k_scan_blk(int* __restrict__ blk) {
    __shared__ int s[1024];
    int t = threadIdx.x;
    int v = (t < NB) ? blk[t] : 0;
    s[t] = v;
    __syncthreads();
    for (int off = 1; off < 1024; off <<= 1) {
        int u = (t >= off) ? s[t - off] : 0;
        __syncthreads();
        s[t] += u;
        __syncthreads();
    }
    if (t < NB) blk[t] = (t == 0) ? 0 : s[t - 1];
}

__global__ void k_scan_final(const int* __restrict__ deg, const int* __restrict__ blk,
                             int* __restrict__ row_off, float* __restrict__ d_inv) {
    __shared__ int s[256];
    int t = threadIdx.x;
    int i = blockIdx.x * 256 + t;
    int v = (i < NN) ? deg[i] : 0;
    s[t] = v;
    __syncthreads();
    for (int off = 1; off < 256; off <<= 1) {
        int u = (t >= off) ? s[t - off] : 0;
        __syncthreads();
        s[t] += u;
        __syncthreads();
    }
    if (i < NN) {
        row_off[i] = blk[blockIdx.x] + s[t] - v;
        d_inv[i]   = (v > 0) ? rsqrtf((float)v) : 0.f;
    }
    if (i == 0) row_off[NN] = NE;
}

__global__ void k_scatter(const int* __restrict__ h, const int* __restrict__ t,
                          const int* __restrict__ row_off, int* __restrict__ row_cur,
                          const float* __restrict__ d_inv,
                          int2* __restrict__ csr) {
    int e = blockIdx.x * blockDim.x + threadIdx.x;
    if (e >= NE) return;
    int hh = h[e], tt = t[e];
    int slot = row_off[hh] + atomicAdd(&row_cur[hh], 1);
    csr[slot] = make_int2(tt, __float_as_int(d_inv[hh] * d_inv[tt]));
}

// ---------------- init / transpose ----------------

__global__ void k_init(const float* __restrict__ emb, float* __restrict__ xt,
                       float* __restrict__ acc, unsigned* __restrict__ pkA) {
    int i = blockIdx.x * blockDim.x + threadIdx.x;   // < NN*32
    if (i >= NN * 32) return;
    float2 v = ((const float2*)emb)[i];
    ((float2*)xt)[i]  = v;
    ((float2*)acc)[i] = v;
    pkA[(size_t)(i >> 5) * ROWD + 64 + (i & 31)] = pack_bf16x2(v.x, v.y);
}

// WtG[m][k][d] = W_m[d][k]; m=0 user, m=1 item
__global__ void k_wt(const float* __restrict__ Wu, const float* __restrict__ Wi,
                     float* __restrict__ WtG) {
    int i = blockIdx.x * blockDim.x + threadIdx.x;   // < 2*8192
    if (i >= 2 * D * KDIM) return;
    int m = i >> 13, r = i & 8191;
    int k = r >> 6, d = r & 63;
    const float* W = m ? Wi : Wu;
    WtG[m * 8192 + k * 64 + d] = W[d * KDIM + k];
}

// ---------------- k_gnn: SPMM(bf16 gather) + norm + pack ----------------
__global__ __launch_bounds__(256) void k_gnn(const int* __restrict__ row_off,
                                             const int2* __restrict__ csr,
                                             unsigned* __restrict__ pk,
                                             const float* __restrict__ xt,
                                             float* __restrict__ base_) {
    int wid  = (blockIdx.x * blockDim.x + threadIdx.x) >> 6;
    int lane = threadIdx.x & 63;
    if (wid >= NN) return;
    int half = lane >> 5, l32 = lane & 31;
    int s = row_off[wid], eend = row_off[wid + 1];
    float ax = 0.f, ay = 0.f;
    int e = s;
    for (; e + 3 < eend; e += 4) {
        int2 tg0 = csr[e + half];
        int2 tg1 = csr[e + 2 + half];
        unsigned x0 = pk[(size_t)tg0.x * ROWD + 64 + l32];
        unsigned x1 = pk[(size_t)tg1.x * ROWD + 64 + l32];
        float g0 = __int_as_float(tg0.y), g1 = __int_as_float(tg1.y);
        ax = fmaf(g0, bf_lo(x0), ax); ay = fmaf(g0, bf_hi(x0), ay);
        ax = fmaf(g1, bf_lo(x1), ax); ay = fmaf(g1, bf_hi(x1), ay);
    }
    for (; e < eend; e += 2) {
        int ee = e + half;
        int2 tg = csr[min(ee, eend - 1)];
        float gv = (ee < eend) ? __int_as_float(tg.y) : 0.f;
        unsigned xw = pk[(size_t)tg.x * ROWD + 64 + l32];
        ax = fmaf(gv, bf_lo(xw), ax); ay = fmaf(gv, bf_hi(xw), ay);
    }
    ax += __shfl_xor(ax, 32); ay += __shfl_xor(ay, 32);
    float ss = fmaf(ax, ax, ay * ay);
    #pragma unroll
    for (int m = 1; m <= 16; m <<= 1) ss += __shfl_xor(ss, m);
    float inv = 1.f / fmaxf(sqrtf(ss), EPSF);
    if (half == 0) {
        pk[(size_t)wid * ROWD + l32] = pack_bf16x2(ax * inv, ay * inv);
        size_t idx = (size_t)wid * 32 + l32;
        float2 xr = ((const float2*)xt)[idx];
        ((float2*)base_)[idx] = make_float2(ax + xr.x, ay + xr.y);
    }
}

// ---------------- k_int: softmax(x@W)@W^T, 64-node tile, high-occupancy ------
// LDS: union( xs_t[64][68] f32 , ps[64][66] bf16x2 )  = 17408 B
__global__ __launch_bounds__(256) void k_int(const float* __restrict__ xt,
                                             const float* __restrict__ Wu,
                                             const float* __restrict__ Wi,
                                             const float* __restrict__ WtG,
                                             unsigned* __restrict__ pk,
                                             float* __restrict__ base_) {
    __shared__ float xs[64 * 68];
    unsigned* psU = (unsigned*)xs;     // [64][66] packed bf16 pairs

    const float* W;
    const float* Wt;
    int bse, count, n0;
    if (blockIdx.x < TU) {
        W = Wu; Wt = WtG;        bse = 0;       count = N_USERS; n0 = blockIdx.x * 64;
    } else {
        W = Wi; Wt = WtG + 8192; bse = N_USERS; count = N_ITEMS; n0 = (blockIdx.x - TU) * 64;
    }

    int tid = threadIdx.x;
    for (int i = tid; i < 64 * 64; i += 256) {
        int nl = i >> 6, d = i & 63;
        int n  = n0 + nl;
        float v = (n < count) ? xt[(size_t)(bse + n) * D + d] : 0.f;
        xs[d * 68 + nl] = v;
    }
    __syncthreads();

    int wv = tid >> 6;
    int la = tid & 63;
    int ag = la >> 4;        // node sub-group 0..3
    int bg = la & 15;        // k/d sub-group 0..15
    int nbase = wv * 16 + ag * 4;

    // phase 1: logits. lane owns nodes nbase+i, k = 4*bg + 64*j + c
    float acc[4][8];
    #pragma unroll
    for (int i = 0; i < 4; ++i)
        #pragma unroll
        for (int j = 0; j < 8; ++j) acc[i][j] = 0.f;

    #pragma unroll 4
    for (int d = 0; d < 64; ++d) {
        float4 xv = *(const float4*)&xs[d * 68 + nbase];
        float4 wa = *(const float4*)&W[d * KDIM + 4 * bg];
        float4 wb = *(const float4*)&W[d * KDIM + 64 + 4 * bg];
        float xx[4] = {xv.x, xv.y, xv.z, xv.w};
        float wk[8] = {wa.x, wa.y, wa.z, wa.w, wb.x, wb.y, wb.z, wb.w};
        #pragma unroll
        for (int i = 0; i < 4; ++i)
            #pragma unroll
            for (int j = 0; j < 8; ++j)
                acc[i][j] = fmaf(xx[i], wk[j], acc[i][j]);
    }

    // softmax over k per node (reduce across bg lanes)
    float p[4][8];
    float inv_s[4];
    #pragma unroll
    for (int i = 0; i < 4; ++i) {
        float m = acc[i][0];
        #pragma unroll
        for (int j = 1; j < 8; ++j) m = fmaxf(m, acc[i][j]);
        m = fmaxf(m, __shfl_xor(m, 1));
        m = fmaxf(m, __shfl_xor(m, 2));
        m = fmaxf(m, __shfl_xor(m, 4));
        m = fmaxf(m, __shfl_xor(m, 8));
        float sm = 0.f;
        #pragma unroll
        for (int j = 0; j < 8; ++j) { p[i][j] = __expf(acc[i][j] - m); sm += p[i][j]; }
        sm += __shfl_xor(sm, 1);
        sm += __shfl_xor(sm, 2);
        sm += __shfl_xor(sm, 4);
        sm += __shfl_xor(sm, 8);
        inv_s[i] = 1.f / sm;
    }

    __syncthreads();   // xs reads done before ps overwrites

    #pragma unroll
    for (int i = 0; i < 4; ++i) {
        float is = inv_s[i];
        #pragma unroll
        for (int j = 0; j < 2; ++j) {
            unsigned u0 = pack_bf16x2(p[i][4 * j + 0] * is, p[i][4 * j + 1] * is);
            unsigned u1 = pack_bf16x2(p[i][4 * j + 2] * is, p[i][4 * j + 3] * is);
            *(uint2*)&psU[(nbase + i) * 66 + 2 * bg + 32 * j] = make_uint2(u0, u1);
        }
    }
    __syncthreads();

    // phase 2: out[n][d] = sum_k P[n][k] * Wt[k][d]; lane owns 4n x d=4*bg+r
    float o[4][4];
    #pragma unroll
    for (int i = 0; i < 4; ++i)
        #pragma unroll
        for (int r = 0; r < 4; ++r) o[i][r] = 0.f;

    int dbase = bg * 4;
    for (int kk = 0; kk < 32; ++kk) {
        uint2 P[4];
        #pragma unroll
        for (int i = 0; i < 4; ++i)
            P[i] = *(const uint2*)&psU[(nbase + i) * 66 + 2 * kk];
        float4 Wv[4];
        #pragma unroll
        for (int c = 0; c < 4; ++c)
            Wv[c] = *(const float4*)&Wt[(4 * kk + c) * 64 + dbase];
        #pragma unroll
        for (int i = 0; i < 4; ++i) {
            float pc[4] = {bf_lo(P[i].x), bf_hi(P[i].x), bf_lo(P[i].y), bf_hi(P[i].y)};
            #pragma unroll
            for (int c = 0; c < 4; ++c) {
                o[i][0] = fmaf(pc[c], Wv[c].x, o[i][0]);
                o[i][1] = fmaf(pc[c], Wv[c].y, o[i][1]);
                o[i][2] = fmaf(pc[c], Wv[c].z, o[i][2]);
                o[i][3] = fmaf(pc[c], Wv[c].w, o[i][3]);
            }
        }
    }

    // epilogue: norm over d, base_ += intl, pk.in-hat
    #pragma unroll
    for (int i = 0; i < 4; ++i) {
        int n = n0 + nbase + i;
        float ss = o[i][0]*o[i][0] + o[i][1]*o[i][1] + o[i][2]*o[i][2] + o[i][3]*o[i][3];
        ss += __shfl_xor(ss, 1);
        ss += __shfl_xor(ss, 2);
        ss += __shfl_xor(ss, 4);
        ss += __shfl_xor(ss, 8);
        if (n < count) {
            size_t g = (size_t)(bse + n);
            float invn = 1.0f / fmaxf(sqrtf(ss), EPSF);
            float4* bp = (float4*)&base_[g * D + dbase];
            float4 bv = *bp;
            bv.x += o[i][0]; bv.y += o[i][1]; bv.z += o[i][2]; bv.w += o[i][3];
            *bp = bv;
            unsigned d0 = pack_bf16x2(o[i][0] * invn, o[i][1] * invn);
            unsigned d1 = pack_bf16x2(o[i][2] * invn, o[i][3] * invn);
            unsigned* pr = pk + g * ROWD + 32;
            ((uint2*)pr)[bg] = make_uint2(d0, d1);
        }
    }
}

// ---------------- k_fused: alphas + gaa/iaa + combine ----------------
__global__ __launch_bounds__(256) void k_fused(const int* __restrict__ row_off,
                                               const int2* __restrict__ csr,
                                               const unsigned* __restrict__ pk,
                                               const float* __restrict__ base_,
                                               float* __restrict__ xt,
                                               unsigned* __restrict__ pknext,
                                               float* __restrict__ acc) {
    int wid  = (blockIdx.x * blockDim.x + threadIdx.x) >> 6;
    int lane = threadIdx.x & 63;
    if (wid >= NN) return;
    int half = lane >> 5, l32 = lane & 31;

    const unsigned* ph = pk + (size_t)wid * ROWD;
    unsigned ugh = ph[l32];
    unsigned uih = ph[32 + l32];
    float hgx = bf_lo(ugh), hgy = bf_hi(ugh);
    float hix = bf_lo(uih), hiy = bf_hi(uih);

    int s = row_off[wid], eend = row_off[wid + 1];
    float sg = 0.f, si = 0.f;
    float agx = 0.f, agy = 0.f, aix = 0.f, aiy = 0.f;

    int e = s;
    for (; e + 3 < eend; e += 4) {
        int t0 = csr[e + half].x;
        int t1 = csr[e + 2 + half].x;
        const unsigned* p0 = pk + (size_t)t0 * ROWD;
        const unsigned* p1 = pk + (size_t)t1 * ROWD;
        unsigned ug0 = p0[l32], ui0 = p0[32 + l32], ux0 = p0[64 + l32];
        unsigned ug1 = p1[l32], ui1 = p1[32 + l32], ux1 = p1[64 + l32];
        float pg0 = fmaf(hgx, bf_lo(ug0), hgy * bf_hi(ug0));
        float pi0 = fmaf(hix, bf_lo(ui0), hiy * bf_hi(ui0));
        float pg1 = fmaf(hgx, bf_lo(ug1), hgy * bf_hi(ug1));
        float pi1 = fmaf(hix, bf_lo(ui1), hiy * bf_hi(ui1));
        #pragma unroll
        for (int m = 1; m <= 16; m <<= 1) {
            pg0 += __shfl_xor(pg0, m); pi0 += __shfl_xor(pi0, m);
            pg1 += __shfl_xor(pg1, m); pi1 += __shfl_xor(pi1, m);
        }
        float ag0 = fmaf(pg0, 0.5f, 0.5f), ai0 = fmaf(pi0, 0.5f, 0.5f);
        float ag1 = fmaf(pg1, 0.5f, 0.5f), ai1 = fmaf(pi1, 0.5f, 0.5f);
        sg += ag0 + ag1; si += ai0 + ai1;
        float x0l = bf_lo(ux0), x0h = bf_hi(ux0);
        float x1l = bf_lo(ux1), x1h = bf_hi(ux1);
        agx = fmaf(ag0, x0l, agx); agy = fmaf(ag0, x0h, agy);
        aix = fmaf(ai0, x0l, aix); aiy = fmaf(ai0, x0h, aiy);
        agx = fmaf(ag1, x1l, agx); agy = fmaf(ag1, x1h, agy);
        aix = fmaf(ai1, x1l, aix); aiy = fmaf(ai1, x1h, aiy);
    }
    for (; e < eend; e += 2) {
        int ee = e + half;
        int t  = csr[min(ee, eend - 1)].x;
        const unsigned* pr = pk + (size_t)t * ROWD;
        unsigned ug = pr[l32], ui = pr[32 + l32], ux = pr[64 + l32];
        float pg = fmaf(hgx, bf_lo(ug), hgy * bf_hi(ug));
        float pi = fmaf(hix, bf_lo(ui), hiy * bf_hi(ui));
        #pragma unroll
        for (int m = 1; m <= 16; m <<= 1) {
            pg += __shfl_xor(pg, m); pi += __shfl_xor(pi, m);
        }
        float ag = fmaf(pg, 0.5f, 0.5f);
        float ai = fmaf(pi, 0.5f, 0.5f);
        if (ee >= eend) { ag = 0.f; ai = 0.f; }
        sg += ag; si += ai;
        float xl = bf_lo(ux), xh = bf_hi(ux);
        agx = fmaf(ag, xl, agx); agy = fmaf(ag, xh, agy);
        aix = fmaf(ai, xl, aix); aiy = fmaf(ai, xh, aiy);
    }

    sg  += __shfl_xor(sg, 32);  si  += __shfl_xor(si, 32);
    agx += __shfl_xor(agx, 32); agy += __shfl_xor(agy, 32);
    aix += __shfl_xor(aix, 32); aiy += __shfl_xor(aiy, 32);

    if (half == 0) {
        float invg = sg > 0.f ? 1.f / sg : 0.f;
        float invi = si > 0.f ? 1.f / si : 0.f;
        size_t idx = (size_t)wid * 32 + l32;
        float2 b = ((const float2*)base_)[idx];
        float nx = b.x + invg * agx + invi * aix;
        float ny = b.y + invg * agy + invi * aiy;
        ((float2*)xt)[idx] = make_float2(nx, ny);
        pknext[(size_t)wid * ROWD + 64 + l32] = pack_bf16x2(nx, ny);
        float2 a = ((float2*)acc)[idx];
        a.x += nx; a.y += ny;
        ((float2*)acc)[idx] = a;
    }
}

// ---------------- launch ----------------

extern "C" void kernel_launch(void* const* d_in, const int* in_sizes, int n_in,
                              void* d_out, int out_size, void* d_ws, size_t ws_size,
                              hipStream_t stream) {
    const float* emb   = (const float*)d_in[0];
    const float* Wu    = (const float*)d_in[1];
    const float* Wi    = (const float*)d_in[2];
    const int*   all_h = (const int*)d_in[3];
    const int*   all_t = (const int*)d_in[4];
    float*       acc   = (float*)d_out;

    char*  bp  = (char*)d_ws;
    size_t off = 0;
    auto take = [&](size_t bytes) -> char* {
        char* r = bp + off;
        off = (off + bytes + 255) & ~(size_t)255;
        return r;
    };
    int*      deg     = (int*)     take((size_t)NN * 4);
    int*      row_off = (int*)     take((size_t)(NN + 1) * 4);
    int*      row_cur = (int*)     take((size_t)NN * 4);
    int*      blk     = (int*)     take(1024 * 4);
    float*    d_inv   = (float*)   take((size_t)NN * 4);
    int2*     csr     = (int2*)    take((size_t)NE * 8);
    unsigned* pkA     = (unsigned*)take((size_t)NN * ROWD * 4);
    unsigned* pkB     = (unsigned*)take((size_t)NN * ROWD * 4);
    float*    xt      = (float*)   take((size_t)NN * D * 4);
    float*    base_   = (float*)   take((size_t)NN * D * 4);
    float*    WtG     = (float*)   take((size_t)2 * D * KDIM * 4);
    (void)ws_size; (void)in_sizes; (void)n_in; (void)out_size;

    hipMemsetAsync(deg, 0, (size_t)NN * 4, stream);
    hipMemsetAsync(row_cur, 0, (size_t)NN * 4, stream);

    const int EB = (NE + 255) / 256;
    k_deg<<<EB, 256, 0, stream>>>(all_h, deg);
    k_blk_sum<<<NB, 256, 0, stream>>>(deg, blk);
    k_scan_blk<<<1, 1024, 0, stream>>>(blk);
    k_scan_final<<<NB, 256, 0, stream>>>(deg, blk, row_off, d_inv);
    k_scatter<<<EB, 256, 0, stream>>>(all_h, all_t, row_off, row_cur, d_inv, csr);

    k_init<<<(NN * 32 + 255) / 256, 256, 0, stream>>>(emb, xt, acc, pkA);
    k_wt<<<(2 * D * KDIM + 255) / 256, 256, 0, stream>>>(Wu, Wi, WtG);

    const int RB = (NN + 3) / 4;
    unsigned* cur = pkA;
    unsigned* nxt = pkB;
    for (int l = 0; l < 3; ++l) {
        k_gnn<<<RB, 256, 0, stream>>>(row_off, csr, cur, xt, base_);
        k_int<<<TU + TI, 256, 0, stream>>>(xt, Wu, Wi, WtG, cur, base_);
        k_fused<<<RB, 256, 0, stream>>>(row_off, csr, cur, base_, xt, nxt, acc);
        unsigned* tmp = cur; cur = nxt; nxt = tmp;
    }
}

// Round 6
// 1045.397 us; speedup vs baseline: 1.9180x; 1.0213x over previous
//
#include <hip/hip_runtime.h>

#define N_USERS 90000
#define N_ITEMS 60000
#define NN      (N_USERS + N_ITEMS)   // 150000
#define D       64
#define KDIM    128
#define NE      1600000
#define EPSF    1e-12f
#define ROWD    96                    // pk row = 96 dwords = 384B
#define TU      ((N_USERS + 63) / 64) // 1407
#define TI      ((N_ITEMS + 63) / 64) // 938

// ---------------- f16 helpers ----------------

typedef __fp16 h2 __attribute__((ext_vector_type(2)));

__device__ inline h2 as_h2(unsigned u) {
    union { unsigned u; h2 h; } v; v.u = u; return v.h;
}
__device__ inline unsigned pkrtz(float a, float b) {
    auto r = __builtin_amdgcn_cvt_pkrtz(a, b);
    union { decltype(r) h; unsigned u; } v; v.h = r; return v.u;
}
__device__ inline float fdot2(h2 a, h2 b, float c) {
#if __has_builtin(__builtin_amdgcn_fdot2)
    return __builtin_amdgcn_fdot2(a, b, c, false);
#else
    return c + (float)a.x * (float)b.x + (float)a.y * (float)b.y;
#endif
}

// ---------------- CSR build ----------------

__global__ void k_deg(const int* __restrict__ h, int* __restrict__ deg) {
    int e = blockIdx.x * blockDim.x + threadIdx.x;
    if (e < NE) atomicAdd(&deg[h[e]], 1);
}

__global__ void k_rowoff(const int* __restrict__ deg, int* __restrict__ counter,
                         int* __restrict__ row_off, float* __restrict__ d_inv) {
    int i = blockIdx.x * blockDim.x + threadIdx.x;
    if (i >= NN) return;
    int d = deg[i];
    row_off[i] = atomicAdd(counter, d);
    d_inv[i]   = (d > 0) ? rsqrtf((float)d) : 0.f;
}

__global__ void k_scatter(const int* __restrict__ h, const int* __restrict__ t,
                          const int* __restrict__ row_off, int* __restrict__ row_cur,
                          const float* __restrict__ d_inv,
                          int2* __restrict__ csr) {
    int e = blockIdx.x * blockDim.x + threadIdx.x;
    if (e >= NE) return;
    int hh = h[e], tt = t[e];
    int slot = row_off[hh] + atomicAdd(&row_cur[hh], 1);
    csr[slot] = make_int2(tt, __float_as_int(d_inv[hh] * d_inv[tt]));
}

// ---------------- init / transpose ----------------

__global__ void k_init(const float* __restrict__ emb, float* __restrict__ xt,
                       float* __restrict__ acc, unsigned* __restrict__ pkA) {
    int i = blockIdx.x * blockDim.x + threadIdx.x;   // over NN*16 float4s
    if (i >= NN * 16) return;
    float4 v = ((const float4*)emb)[i];
    ((float4*)xt)[i]  = v;
    ((float4*)acc)[i] = v;
    int row = i >> 4, l = i & 15;
    *(uint2*)&pkA[(size_t)row * ROWD + 64 + 2 * l] =
        make_uint2(pkrtz(v.x, v.y), pkrtz(v.z, v.w));
}

// WtG[m][k][d] = W_m[d][k]
__global__ void k_wt(const float* __restrict__ Wu, const float* __restrict__ Wi,
                     float* __restrict__ WtG) {
    int i = blockIdx.x * blockDim.x + threadIdx.x;
    if (i >= 2 * D * KDIM) return;
    int m = i >> 13, r = i & 8191;
    int k = r >> 6, d = r & 63;
    const float* W = m ? Wi : Wu;
    WtG[m * 8192 + k * 64 + d] = W[d * KDIM + k];
}

// ---------------- k_gnn: SPMM(f16 gather) + norm + pack ----------------
// wave = 4 groups x 16 lanes; group g handles edge e+g; lane l16 owns dims 4*l16..+3
__global__ __launch_bounds__(256) void k_gnn(const int* __restrict__ row_off,
                                             const int* __restrict__ deg,
                                             const int2* __restrict__ csr,
                                             unsigned* __restrict__ pk,
                                             const float* __restrict__ xt,
                                             float* __restrict__ base_) {
    int wid  = (blockIdx.x * blockDim.x + threadIdx.x) >> 6;
    int lane = threadIdx.x & 63;
    if (wid >= NN) return;
    int grp = lane >> 4, l16 = lane & 15;
    int s = row_off[wid], eend = s + deg[wid];
    float a0 = 0.f, a1 = 0.f, a2 = 0.f, a3 = 0.f;
    int e = s;
    for (; e + 7 < eend; e += 8) {
        int2 cA = csr[e + grp];
        int2 cB = csr[e + 4 + grp];
        uint2 wA = *(const uint2*)&pk[(size_t)cA.x * ROWD + 64 + 2 * l16];
        uint2 wB = *(const uint2*)&pk[(size_t)cB.x * ROWD + 64 + 2 * l16];
        float gA = __int_as_float(cA.y), gB = __int_as_float(cB.y);
        h2 xa0 = as_h2(wA.x), xa1 = as_h2(wA.y);
        h2 xb0 = as_h2(wB.x), xb1 = as_h2(wB.y);
        a0 = fmaf(gA, (float)xa0.x, a0); a1 = fmaf(gA, (float)xa0.y, a1);
        a2 = fmaf(gA, (float)xa1.x, a2); a3 = fmaf(gA, (float)xa1.y, a3);
        a0 = fmaf(gB, (float)xb0.x, a0); a1 = fmaf(gB, (float)xb0.y, a1);
        a2 = fmaf(gB, (float)xb1.x, a2); a3 = fmaf(gB, (float)xb1.y, a3);
    }
    for (; e < eend; e += 4) {
        int ee = e + grp;
        bool val = ee < eend;
        int2 c = csr[val ? ee : eend - 1];
        float gv = val ? __int_as_float(c.y) : 0.f;
        uint2 w = *(const uint2*)&pk[(size_t)c.x * ROWD + 64 + 2 * l16];
        h2 x0 = as_h2(w.x), x1 = as_h2(w.y);
        a0 = fmaf(gv, (float)x0.x, a0); a1 = fmaf(gv, (float)x0.y, a1);
        a2 = fmaf(gv, (float)x1.x, a2); a3 = fmaf(gv, (float)x1.y, a3);
    }
    // cross-group reduce (masks 16,32)
    a0 += __shfl_xor(a0, 16); a1 += __shfl_xor(a1, 16);
    a2 += __shfl_xor(a2, 16); a3 += __shfl_xor(a3, 16);
    a0 += __shfl_xor(a0, 32); a1 += __shfl_xor(a1, 32);
    a2 += __shfl_xor(a2, 32); a3 += __shfl_xor(a3, 32);
    float ss = fmaf(a0, a0, fmaf(a1, a1, fmaf(a2, a2, a3 * a3)));
    ss += __shfl_xor(ss, 1); ss += __shfl_xor(ss, 2);
    ss += __shfl_xor(ss, 4); ss += __shfl_xor(ss, 8);
    float inv = 1.f / fmaxf(sqrtf(ss), EPSF);
    if (grp == 0) {
        unsigned* pr = pk + (size_t)wid * ROWD;
        pr[4 * l16]     = pkrtz(a0 * inv, a1 * inv);
        pr[4 * l16 + 2] = pkrtz(a2 * inv, a3 * inv);
        size_t bidx = (size_t)wid * 16 + l16;
        float4 xr = ((const float4*)xt)[bidx];
        float4 bo;
        bo.x = a0 + xr.x; bo.y = a1 + xr.y; bo.z = a2 + xr.z; bo.w = a3 + xr.w;
        ((float4*)base_)[bidx] = bo;
    }
}

// ---------------- k_int: softmax(x@W)@W^T, 64-node tile ----------------
// LDS: union( xs_t[64][68] f32 , ps[64][66] f16x2 ) = 17408 B
__global__ __launch_bounds__(256) void k_int(const float* __restrict__ xt,
                                             const float* __restrict__ Wu,
                                             const float* __restrict__ Wi,
                                             const float* __restrict__ WtG,
                                             unsigned* __restrict__ pk,
                                             float* __restrict__ base_) {
    __shared__ float xs[64 * 68];
    unsigned* psU = (unsigned*)xs;     // [64][66] packed f16 pairs

    const float* W;
    const float* Wt;
    int bse, count, n0;
    if (blockIdx.x < TU) {
        W = Wu; Wt = WtG;        bse = 0;       count = N_USERS; n0 = blockIdx.x * 64;
    } else {
        W = Wi; Wt = WtG + 8192; bse = N_USERS; count = N_ITEMS; n0 = (blockIdx.x - TU) * 64;
    }

    int tid = threadIdx.x;
    for (int i = tid; i < 64 * 64; i += 256) {
        int nl = i >> 6, d = i & 63;
        int n  = n0 + nl;
        float v = (n < count) ? xt[(size_t)(bse + n) * D + d] : 0.f;
        xs[d * 68 + nl] = v;
    }
    __syncthreads();

    int wv = tid >> 6;
    int la = tid & 63;
    int ag = la >> 4;
    int bg = la & 15;
    int nbase = wv * 16 + ag * 4;

    float acc[4][8];
    #pragma unroll
    for (int i = 0; i < 4; ++i)
        #pragma unroll
        for (int j = 0; j < 8; ++j) acc[i][j] = 0.f;

    #pragma unroll 4
    for (int d = 0; d < 64; ++d) {
        float4 xv = *(const float4*)&xs[d * 68 + nbase];
        float4 wa = *(const float4*)&W[d * KDIM + 4 * bg];
        float4 wb = *(const float4*)&W[d * KDIM + 64 + 4 * bg];
        float xx[4] = {xv.x, xv.y, xv.z, xv.w};
        float wk[8] = {wa.x, wa.y, wa.z, wa.w, wb.x, wb.y, wb.z, wb.w};
        #pragma unroll
        for (int i = 0; i < 4; ++i)
            #pragma unroll
            for (int j = 0; j < 8; ++j)
                acc[i][j] = fmaf(xx[i], wk[j], acc[i][j]);
    }

    float p[4][8];
    float inv_s[4];
    #pragma unroll
    for (int i = 0; i < 4; ++i) {
        float m = acc[i][0];
        #pragma unroll
        for (int j = 1; j < 8; ++j) m = fmaxf(m, acc[i][j]);
        m = fmaxf(m, __shfl_xor(m, 1));
        m = fmaxf(m, __shfl_xor(m, 2));
        m = fmaxf(m, __shfl_xor(m, 4));
        m = fmaxf(m, __shfl_xor(m, 8));
        float sm = 0.f;
        #pragma unroll
        for (int j = 0; j < 8; ++j) { p[i][j] = __expf(acc[i][j] - m); sm += p[i][j]; }
        sm += __shfl_xor(sm, 1);
        sm += __shfl_xor(sm, 2);
        sm += __shfl_xor(sm, 4);
        sm += __shfl_xor(sm, 8);
        inv_s[i] = 1.f / sm;
    }

    __syncthreads();

    #pragma unroll
    for (int i = 0; i < 4; ++i) {
        float is = inv_s[i];
        #pragma unroll
        for (int j = 0; j < 2; ++j) {
            unsigned u0 = pkrtz(p[i][4 * j + 0] * is, p[i][4 * j + 1] * is);
            unsigned u1 = pkrtz(p[i][4 * j + 2] * is, p[i][4 * j + 3] * is);
            *(uint2*)&psU[(nbase + i) * 66 + 2 * bg + 32 * j] = make_uint2(u0, u1);
        }
    }
    __syncthreads();

    float o[4][4];
    #pragma unroll
    for (int i = 0; i < 4; ++i)
        #pragma unroll
        for (int r = 0; r < 4; ++r) o[i][r] = 0.f;

    int dbase = bg * 4;
    for (int kk = 0; kk < 32; ++kk) {
        uint2 P[4];
        #pragma unroll
        for (int i = 0; i < 4; ++i)
            P[i] = *(const uint2*)&psU[(nbase + i) * 66 + 2 * kk];
        float4 Wv[4];
        #pragma unroll
        for (int c = 0; c < 4; ++c)
            Wv[c] = *(const float4*)&Wt[(4 * kk + c) * 64 + dbase];
        #pragma unroll
        for (int i = 0; i < 4; ++i) {
            h2 pa = as_h2(P[i].x), pb = as_h2(P[i].y);
            float pc[4] = {(float)pa.x, (float)pa.y, (float)pb.x, (float)pb.y};
            #pragma unroll
            for (int c = 0; c < 4; ++c) {
                o[i][0] = fmaf(pc[c], Wv[c].x, o[i][0]);
                o[i][1] = fmaf(pc[c], Wv[c].y, o[i][1]);
                o[i][2] = fmaf(pc[c], Wv[c].z, o[i][2]);
                o[i][3] = fmaf(pc[c], Wv[c].w, o[i][3]);
            }
        }
    }

    #pragma unroll
    for (int i = 0; i < 4; ++i) {
        int n = n0 + nbase + i;
        float ss = o[i][0]*o[i][0] + o[i][1]*o[i][1] + o[i][2]*o[i][2] + o[i][3]*o[i][3];
        ss += __shfl_xor(ss, 1);
        ss += __shfl_xor(ss, 2);
        ss += __shfl_xor(ss, 4);
        ss += __shfl_xor(ss, 8);
        if (n < count) {
            size_t g = (size_t)(bse + n);
            float invn = 1.0f / fmaxf(sqrtf(ss), EPSF);
            float4* bp = (float4*)&base_[g * D + dbase];
            float4 bv = *bp;
            bv.x += o[i][0]; bv.y += o[i][1]; bv.z += o[i][2]; bv.w += o[i][3];
            *bp = bv;
            unsigned* pr = pk + g * ROWD;
            pr[4 * bg + 1] = pkrtz(o[i][0] * invn, o[i][1] * invn);
            pr[4 * bg + 3] = pkrtz(o[i][2] * invn, o[i][3] * invn);
        }
    }
}

// ---------------- k_fused: alphas + gaa/iaa + combine ----------------
// wave = 4 groups x 16 lanes; group g handles edge e+g; lane l16 owns dims 4*l16..+3
__global__ __launch_bounds__(256) void k_fused(const int* __restrict__ row_off,
                                               const int* __restrict__ deg,
                                               const int2* __restrict__ csr,
                                               const unsigned* __restrict__ pk,
                                               const float* __restrict__ base_,
                                               float* __restrict__ xt,
                                               unsigned* __restrict__ pknext,
                                               float* __restrict__ acc) {
    int wid  = (blockIdx.x * blockDim.x + threadIdx.x) >> 6;
    int lane = threadIdx.x & 63;
    if (wid >= NN) return;
    int grp = lane >> 4, l16 = lane & 15;

    const unsigned* ph = pk + (size_t)wid * ROWD;
    uint4 hq = *(const uint4*)&ph[4 * l16];
    h2 hg0 = as_h2(hq.x), hi0 = as_h2(hq.y), hg1 = as_h2(hq.z), hi1 = as_h2(hq.w);

    int s = row_off[wid], eend = s + deg[wid];
    float sg = 0.f, si = 0.f;
    float g0 = 0.f, g1 = 0.f, g2 = 0.f, g3 = 0.f;
    float i0 = 0.f, i1 = 0.f, i2 = 0.f, i3 = 0.f;

    int e = s;
    for (; e + 7 < eend; e += 8) {
        int tA = csr[e + grp].x;
        int tB = csr[e + 4 + grp].x;
        const unsigned* pA = pk + (size_t)tA * ROWD;
        const unsigned* pB = pk + (size_t)tB * ROWD;
        uint4 qA = *(const uint4*)&pA[4 * l16];
        uint2 wA = *(const uint2*)&pA[64 + 2 * l16];
        uint4 qB = *(const uint4*)&pB[4 * l16];
        uint2 wB = *(const uint2*)&pB[64 + 2 * l16];
        float pgA = fdot2(hg0, as_h2(qA.x), fdot2(hg1, as_h2(qA.z), 0.f));
        float piA = fdot2(hi0, as_h2(qA.y), fdot2(hi1, as_h2(qA.w), 0.f));
        float pgB = fdot2(hg0, as_h2(qB.x), fdot2(hg1, as_h2(qB.z), 0.f));
        float piB = fdot2(hi0, as_h2(qB.y), fdot2(hi1, as_h2(qB.w), 0.f));
        #pragma unroll
        for (int m = 1; m <= 8; m <<= 1) {
            pgA += __shfl_xor(pgA, m); piA += __shfl_xor(piA, m);
            pgB += __shfl_xor(pgB, m); piB += __shfl_xor(piB, m);
        }
        float agA = fmaf(pgA, 0.5f, 0.5f), aiA = fmaf(piA, 0.5f, 0.5f);
        float agB = fmaf(pgB, 0.5f, 0.5f), aiB = fmaf(piB, 0.5f, 0.5f);
        sg += agA + agB; si += aiA + aiB;
        h2 xa0 = as_h2(wA.x), xa1 = as_h2(wA.y);
        h2 xb0 = as_h2(wB.x), xb1 = as_h2(wB.y);
        float xA[4] = {(float)xa0.x, (float)xa0.y, (float)xa1.x, (float)xa1.y};
        float xB[4] = {(float)xb0.x, (float)xb0.y, (float)xb1.x, (float)xb1.y};
        g0 = fmaf(agA, xA[0], g0); g1 = fmaf(agA, xA[1], g1);
        g2 = fmaf(agA, xA[2], g2); g3 = fmaf(agA, xA[3], g3);
        i0 = fmaf(aiA, xA[0], i0); i1 = fmaf(aiA, xA[1], i1);
        i2 = fmaf(aiA, xA[2], i2); i3 = fmaf(aiA, xA[3], i3);
        g0 = fmaf(agB, xB[0], g0); g1 = fmaf(agB, xB[1], g1);
        g2 = fmaf(agB, xB[2], g2); g3 = fmaf(agB, xB[3], g3);
        i0 = fmaf(aiB, xB[0], i0); i1 = fmaf(aiB, xB[1], i1);
        i2 = fmaf(aiB, xB[2], i2); i3 = fmaf(aiB, xB[3], i3);
    }
    for (; e < eend; e += 4) {
        int ee = e + grp;
        bool val = ee < eend;
        int t = csr[val ? ee : eend - 1].x;
        const unsigned* pr = pk + (size_t)t * ROWD;
        uint4 q = *(const uint4*)&pr[4 * l16];
        uint2 w = *(const uint2*)&pr[64 + 2 * l16];
        float pg = fdot2(hg0, as_h2(q.x), fdot2(hg1, as_h2(q.z), 0.f));
        float pi = fdot2(hi0, as_h2(q.y), fdot2(hi1, as_h2(q.w), 0.f));
        #pragma unroll
        for (int m = 1; m <= 8; m <<= 1) {
            pg += __shfl_xor(pg, m); pi += __shfl_xor(pi, m);
        }
        float ag = fmaf(pg, 0.5f, 0.5f), ai = fmaf(pi, 0.5f, 0.5f);
        if (!val) { ag = 0.f; ai = 0.f; }
        sg += ag; si += ai;
        h2 x0 = as_h2(w.x), x1 = as_h2(w.y);
        float xv[4] = {(float)x0.x, (float)x0.y, (float)x1.x, (float)x1.y};
        g0 = fmaf(ag, xv[0], g0); g1 = fmaf(ag, xv[1], g1);
        g2 = fmaf(ag, xv[2], g2); g3 = fmaf(ag, xv[3], g3);
        i0 = fmaf(ai, xv[0], i0); i1 = fmaf(ai, xv[1], i1);
        i2 = fmaf(ai, xv[2], i2); i3 = fmaf(ai, xv[3], i3);
    }

    // cross-group reduce (masks 16,32) for 10 values
    #pragma unroll
    for (int m = 16; m <= 32; m <<= 1) {
        sg += __shfl_xor(sg, m); si += __shfl_xor(si, m);
        g0 += __shfl_xor(g0, m); g1 += __shfl_xor(g1, m);
        g2 += __shfl_xor(g2, m); g3 += __shfl_xor(g3, m);
        i0 += __shfl_xor(i0, m); i1 += __shfl_xor(i1, m);
        i2 += __shfl_xor(i2, m); i3 += __shfl_xor(i3, m);
    }

    if (grp == 0) {
        float invg = sg > 0.f ? 1.f / sg : 0.f;
        float invi = si > 0.f ? 1.f / si : 0.f;
        size_t bidx = (size_t)wid * 16 + l16;
        float4 b = ((const float4*)base_)[bidx];
        float o0 = b.x + invg * g0 + invi * i0;
        float o1 = b.y + invg * g1 + invi * i1;
        float o2 = b.z + invg * g2 + invi * i2;
        float o3 = b.w + invg * g3 + invi * i3;
        float4 ov; ov.x = o0; ov.y = o1; ov.z = o2; ov.w = o3;
        ((float4*)xt)[bidx] = ov;
        *(uint2*)&pknext[(size_t)wid * ROWD + 64 + 2 * l16] =
            make_uint2(pkrtz(o0, o1), pkrtz(o2, o3));
        float4 a = ((float4*)acc)[bidx];
        a.x += o0; a.y += o1; a.z += o2; a.w += o3;
        ((float4*)acc)[bidx] = a;
    }
}

// ---------------- launch ----------------

extern "C" void kernel_launch(void* const* d_in, const int* in_sizes, int n_in,
                              void* d_out, int out_size, void* d_ws, size_t ws_size,
                              hipStream_t stream) {
    const float* emb   = (const float*)d_in[0];
    const float* Wu    = (const float*)d_in[1];
    const float* Wi    = (const float*)d_in[2];
    const int*   all_h = (const int*)d_in[3];
    const int*   all_t = (const int*)d_in[4];
    float*       acc   = (float*)d_out;

    char*  bp  = (char*)d_ws;
    size_t off = 0;
    auto take = [&](size_t bytes) -> char* {
        char* r = bp + off;
        off = (off + bytes + 255) & ~(size_t)255;
        return r;
    };
    int*      deg     = (int*)     take((size_t)NN * 4);
    int*      row_off = (int*)     take((size_t)NN * 4);
    int*      row_cur = (int*)     take((size_t)NN * 4);
    int*      counter = (int*)     take(256);
    float*    d_inv   = (float*)   take((size_t)NN * 4);
    int2*     csr     = (int2*)    take((size_t)NE * 8);
    unsigned* pkA     = (unsigned*)take((size_t)NN * ROWD * 4);
    unsigned* pkB     = (unsigned*)take((size_t)NN * ROWD * 4);
    float*    xt      = (float*)   take((size_t)NN * D * 4);
    float*    base_   = (float*)   take((size_t)NN * D * 4);
    float*    WtG     = (float*)   take((size_t)2 * D * KDIM * 4);
    (void)ws_size; (void)in_sizes; (void)n_in; (void)out_size;

    hipMemsetAsync(deg, 0, (size_t)NN * 4, stream);
    hipMemsetAsync(row_cur, 0, (size_t)NN * 4, stream);
    hipMemsetAsync(counter, 0, 256, stream);

    const int EB = (NE + 255) / 256;
    const int NBK = (NN + 255) / 256;
    k_deg<<<EB, 256, 0, stream>>>(all_h, deg);
    k_rowoff<<<NBK, 256, 0, stream>>>(deg, counter, row_off, d_inv);
    k_scatter<<<EB, 256, 0, stream>>>(all_h, all_t, row_off, row_cur, d_inv, csr);

    k_init<<<(NN * 16 + 255) / 256, 256, 0, stream>>>(emb, xt, acc, pkA);
    k_wt<<<(2 * D * KDIM + 255) / 256, 256, 0, stream>>>(Wu, Wi, WtG);

    const int RB = (NN + 3) / 4;
    unsigned* cur = pkA;
    unsigned* nxt = pkB;
    for (int l = 0; l < 3; ++l) {
        k_gnn<<<RB, 256, 0, stream>>>(row_off, deg, csr, cur, xt, base_);
        k_int<<<TU + TI, 256, 0, stream>>>(xt, Wu, Wi, WtG, cur, base_);
        k_fused<<<RB, 256, 0, stream>>>(row_off, deg, csr, cur, base_, xt, nxt, acc);
        unsigned* tmp = cur; cur = nxt; nxt = tmp;
    }
}

// Round 7
// 1042.119 us; speedup vs baseline: 1.9240x; 1.0031x over previous
//
#include <hip/hip_runtime.h>

#define N_USERS 90000
#define N_ITEMS 60000
#define NN      (N_USERS + N_ITEMS)   // 150000
#define D       64
#define KDIM    128
#define NE      1600000
#define EPSF    1e-12f
#define ROWD    96                    // pk row = 96 dwords = 384B
#define TU      ((N_USERS + 63) / 64) // 1407
#define TI      ((N_ITEMS + 63) / 64) // 938
#define NINT    (TU + TI)             // 2345 intent blocks

// ---------------- f16 helpers ----------------

typedef __fp16 h2 __attribute__((ext_vector_type(2)));

__device__ inline h2 as_h2(unsigned u) {
    union { unsigned u; h2 h; } v; v.u = u; return v.h;
}
__device__ inline unsigned pkrtz(float a, float b) {
    auto r = __builtin_amdgcn_cvt_pkrtz(a, b);
    union { decltype(r) h; unsigned u; } v; v.h = r; return v.u;
}
__device__ inline float fdot2(h2 a, h2 b, float c) {
#if __has_builtin(__builtin_amdgcn_fdot2)
    return __builtin_amdgcn_fdot2(a, b, c, false);
#else
    return c + (float)a.x * (float)b.x + (float)a.y * (float)b.y;
#endif
}

// ---------------- CSR build ----------------

__global__ void k_deg(const int* __restrict__ h, int* __restrict__ deg) {
    int e = blockIdx.x * blockDim.x + threadIdx.x;
    if (e < NE) atomicAdd(&deg[h[e]], 1);
}

__global__ void k_rowoff(const int* __restrict__ deg, int* __restrict__ counter,
                         int* __restrict__ row_off, float* __restrict__ d_inv) {
    int i = blockIdx.x * blockDim.x + threadIdx.x;
    if (i >= NN) return;
    int d = deg[i];
    row_off[i] = atomicAdd(counter, d);
    d_inv[i]   = (d > 0) ? rsqrtf((float)d) : 0.f;
}

__global__ void k_scatter(const int* __restrict__ h, const int* __restrict__ t,
                          const int* __restrict__ row_off, int* __restrict__ row_cur,
                          const float* __restrict__ d_inv,
                          int2* __restrict__ csr) {
    int e = blockIdx.x * blockDim.x + threadIdx.x;
    if (e >= NE) return;
    int hh = h[e], tt = t[e];
    int slot = row_off[hh] + atomicAdd(&row_cur[hh], 1);
    csr[slot] = make_int2(tt, __float_as_int(d_inv[hh] * d_inv[tt]));
}

// ---------------- init / transpose ----------------

__global__ void k_init(const float* __restrict__ emb, float* __restrict__ xt,
                       float* __restrict__ acc, unsigned* __restrict__ pkA) {
    int i = blockIdx.x * blockDim.x + threadIdx.x;   // over NN*16 float4s
    if (i >= NN * 16) return;
    float4 v = ((const float4*)emb)[i];
    ((float4*)xt)[i]  = v;
    ((float4*)acc)[i] = v;
    int row = i >> 4, l = i & 15;
    *(uint2*)&pkA[(size_t)row * ROWD + 64 + 2 * l] =
        make_uint2(pkrtz(v.x, v.y), pkrtz(v.z, v.w));
}

// WtG[m][k][d] = W_m[d][k]
__global__ void k_wt(const float* __restrict__ Wu, const float* __restrict__ Wi,
                     float* __restrict__ WtG) {
    int i = blockIdx.x * blockDim.x + threadIdx.x;
    if (i >= 2 * D * KDIM) return;
    int m = i >> 13, r = i & 8191;
    int k = r >> 6, d = r & 63;
    const float* W = m ? Wi : Wu;
    WtG[m * 8192 + k * 64 + d] = W[d * KDIM + k];
}

// ---------------- k_mid: block-specialized  gnn-SPMM  ||  intent ----------------
// blocks [0, NINT)        : intent  softmax(x@W)@W^T -> ihat(pk) + intl_raw(pknx)
// blocks [NINT, NINT+RB)  : gnn SPMM (f16 gather)    -> ghat(pk) + base_=gnn+x
__global__ __launch_bounds__(256) void k_mid(const int* __restrict__ row_off,
                                             const int* __restrict__ deg,
                                             const int2* __restrict__ csr,
                                             unsigned* __restrict__ pk,
                                             unsigned* __restrict__ pknx,
                                             const float* __restrict__ xt,
                                             const float* __restrict__ Wu,
                                             const float* __restrict__ Wi,
                                             const float* __restrict__ WtG,
                                             float* __restrict__ base_) {
    __shared__ float xs[64 * 68];      // intent path only
    int tid = threadIdx.x;

    if (blockIdx.x < NINT) {
        // ================= intent path =================
        unsigned* psU = (unsigned*)xs;   // [64][66] packed f16 pairs (union w/ xs)
        const float* W;
        const float* Wt;
        int bse, count, n0;
        if (blockIdx.x < TU) {
            W = Wu; Wt = WtG;        bse = 0;       count = N_USERS; n0 = blockIdx.x * 64;
        } else {
            W = Wi; Wt = WtG + 8192; bse = N_USERS; count = N_ITEMS; n0 = (blockIdx.x - TU) * 64;
        }

        for (int i = tid; i < 64 * 64; i += 256) {
            int nl = i >> 6, d = i & 63;
            int n  = n0 + nl;
            float v = (n < count) ? xt[(size_t)(bse + n) * D + d] : 0.f;
            xs[d * 68 + nl] = v;
        }
        __syncthreads();

        int wv = tid >> 6;
        int la = tid & 63;
        int ag = la >> 4;
        int bg = la & 15;
        int nbase = wv * 16 + ag * 4;

        float acc[4][8];
        #pragma unroll
        for (int i = 0; i < 4; ++i)
            #pragma unroll
            for (int j = 0; j < 8; ++j) acc[i][j] = 0.f;

        #pragma unroll 4
        for (int d = 0; d < 64; ++d) {
            float4 xv = *(const float4*)&xs[d * 68 + nbase];
            float4 wa = *(const float4*)&W[d * KDIM + 4 * bg];
            float4 wb = *(const float4*)&W[d * KDIM + 64 + 4 * bg];
            float xx[4] = {xv.x, xv.y, xv.z, xv.w};
            float wk[8] = {wa.x, wa.y, wa.z, wa.w, wb.x, wb.y, wb.z, wb.w};
            #pragma unroll
            for (int i = 0; i < 4; ++i)
                #pragma unroll
                for (int j = 0; j < 8; ++j)
                    acc[i][j] = fmaf(xx[i], wk[j], acc[i][j]);
        }

        float p[4][8];
        float inv_s[4];
        #pragma unroll
        for (int i = 0; i < 4; ++i) {
            float m = acc[i][0];
            #pragma unroll
            for (int j = 1; j < 8; ++j) m = fmaxf(m, acc[i][j]);
            m = fmaxf(m, __shfl_xor(m, 1));
            m = fmaxf(m, __shfl_xor(m, 2));
            m = fmaxf(m, __shfl_xor(m, 4));
            m = fmaxf(m, __shfl_xor(m, 8));
            float sm = 0.f;
            #pragma unroll
            for (int j = 0; j < 8; ++j) { p[i][j] = __expf(acc[i][j] - m); sm += p[i][j]; }
            sm += __shfl_xor(sm, 1);
            sm += __shfl_xor(sm, 2);
            sm += __shfl_xor(sm, 4);
            sm += __shfl_xor(sm, 8);
            inv_s[i] = 1.f / sm;
        }

        __syncthreads();

        #pragma unroll
        for (int i = 0; i < 4; ++i) {
            float is = inv_s[i];
            #pragma unroll
            for (int j = 0; j < 2; ++j) {
                unsigned u0 = pkrtz(p[i][4 * j + 0] * is, p[i][4 * j + 1] * is);
                unsigned u1 = pkrtz(p[i][4 * j + 2] * is, p[i][4 * j + 3] * is);
                *(uint2*)&psU[(nbase + i) * 66 + 2 * bg + 32 * j] = make_uint2(u0, u1);
            }
        }
        __syncthreads();

        float o[4][4];
        #pragma unroll
        for (int i = 0; i < 4; ++i)
            #pragma unroll
            for (int r = 0; r < 4; ++r) o[i][r] = 0.f;

        int dbase = bg * 4;
        for (int kk = 0; kk < 32; ++kk) {
            uint2 P[4];
            #pragma unroll
            for (int i = 0; i < 4; ++i)
                P[i] = *(const uint2*)&psU[(nbase + i) * 66 + 2 * kk];
            float4 Wv[4];
            #pragma unroll
            for (int c = 0; c < 4; ++c)
                Wv[c] = *(const float4*)&Wt[(4 * kk + c) * 64 + dbase];
            #pragma unroll
            for (int i = 0; i < 4; ++i) {
                h2 pa = as_h2(P[i].x), pb = as_h2(P[i].y);
                float pc[4] = {(float)pa.x, (float)pa.y, (float)pb.x, (float)pb.y};
                #pragma unroll
                for (int c = 0; c < 4; ++c) {
                    o[i][0] = fmaf(pc[c], Wv[c].x, o[i][0]);
                    o[i][1] = fmaf(pc[c], Wv[c].y, o[i][1]);
                    o[i][2] = fmaf(pc[c], Wv[c].z, o[i][2]);
                    o[i][3] = fmaf(pc[c], Wv[c].w, o[i][3]);
                }
            }
        }

        #pragma unroll
        for (int i = 0; i < 4; ++i) {
            int n = n0 + nbase + i;
            float ss = o[i][0]*o[i][0] + o[i][1]*o[i][1] + o[i][2]*o[i][2] + o[i][3]*o[i][3];
            ss += __shfl_xor(ss, 1);
            ss += __shfl_xor(ss, 2);
            ss += __shfl_xor(ss, 4);
            ss += __shfl_xor(ss, 8);
            if (n < count) {
                size_t g = (size_t)(bse + n);
                float invn = 1.0f / fmaxf(sqrtf(ss), EPSF);
                // raw intl -> dead ghat/ihat region of NEXT pk buffer (64 f32)
                ((float4*)(pknx + g * ROWD))[bg] =
                    make_float4(o[i][0], o[i][1], o[i][2], o[i][3]);
                // normalized ihat -> interleaved slots of current pk
                unsigned* pr = pk + g * ROWD;
                pr[4 * bg + 1] = pkrtz(o[i][0] * invn, o[i][1] * invn);
                pr[4 * bg + 3] = pkrtz(o[i][2] * invn, o[i][3] * invn);
            }
        }
    } else {
        // ================= gnn path =================
        int wid  = ((int)blockIdx.x - NINT) * 4 + (tid >> 6);
        int lane = tid & 63;
        if (wid >= NN) return;
        int grp = lane >> 4, l16 = lane & 15;
        int s = row_off[wid], eend = s + deg[wid];
        float a0 = 0.f, a1 = 0.f, a2 = 0.f, a3 = 0.f;
        int e = s;
        for (; e + 7 < eend; e += 8) {
            int2 cA = csr[e + grp];
            int2 cB = csr[e + 4 + grp];
            uint2 wA = *(const uint2*)&pk[(size_t)cA.x * ROWD + 64 + 2 * l16];
            uint2 wB = *(const uint2*)&pk[(size_t)cB.x * ROWD + 64 + 2 * l16];
            float gA = __int_as_float(cA.y), gB = __int_as_float(cB.y);
            h2 xa0 = as_h2(wA.x), xa1 = as_h2(wA.y);
            h2 xb0 = as_h2(wB.x), xb1 = as_h2(wB.y);
            a0 = fmaf(gA, (float)xa0.x, a0); a1 = fmaf(gA, (float)xa0.y, a1);
            a2 = fmaf(gA, (float)xa1.x, a2); a3 = fmaf(gA, (float)xa1.y, a3);
            a0 = fmaf(gB, (float)xb0.x, a0); a1 = fmaf(gB, (float)xb0.y, a1);
            a2 = fmaf(gB, (float)xb1.x, a2); a3 = fmaf(gB, (float)xb1.y, a3);
        }
        for (; e < eend; e += 4) {
            int ee = e + grp;
            bool val = ee < eend;
            int2 c = csr[val ? ee : eend - 1];
            float gv = val ? __int_as_float(c.y) : 0.f;
            uint2 w = *(const uint2*)&pk[(size_t)c.x * ROWD + 64 + 2 * l16];
            h2 x0 = as_h2(w.x), x1 = as_h2(w.y);
            a0 = fmaf(gv, (float)x0.x, a0); a1 = fmaf(gv, (float)x0.y, a1);
            a2 = fmaf(gv, (float)x1.x, a2); a3 = fmaf(gv, (float)x1.y, a3);
        }
        a0 += __shfl_xor(a0, 16); a1 += __shfl_xor(a1, 16);
        a2 += __shfl_xor(a2, 16); a3 += __shfl_xor(a3, 16);
        a0 += __shfl_xor(a0, 32); a1 += __shfl_xor(a1, 32);
        a2 += __shfl_xor(a2, 32); a3 += __shfl_xor(a3, 32);
        float ss = fmaf(a0, a0, fmaf(a1, a1, fmaf(a2, a2, a3 * a3)));
        ss += __shfl_xor(ss, 1); ss += __shfl_xor(ss, 2);
        ss += __shfl_xor(ss, 4); ss += __shfl_xor(ss, 8);
        float inv = 1.f / fmaxf(sqrtf(ss), EPSF);
        if (grp == 0) {
            unsigned* pr = pk + (size_t)wid * ROWD;
            pr[4 * l16]     = pkrtz(a0 * inv, a1 * inv);
            pr[4 * l16 + 2] = pkrtz(a2 * inv, a3 * inv);
            size_t bidx = (size_t)wid * 16 + l16;
            float4 xr = ((const float4*)xt)[bidx];
            float4 bo;
            bo.x = a0 + xr.x; bo.y = a1 + xr.y; bo.z = a2 + xr.z; bo.w = a3 + xr.w;
            ((float4*)base_)[bidx] = bo;
        }
    }
}

// ---------------- k_fused: alphas + gaa/iaa + combine ----------------
// wave = 4 groups x 16 lanes; group g handles edge e+g; lane l16 owns dims 4*l16..+3
__global__ __launch_bounds__(256) void k_fused(const int* __restrict__ row_off,
                                               const int* __restrict__ deg,
                                               const int2* __restrict__ csr,
                                               const unsigned* __restrict__ pk,
                                               const float* __restrict__ base_,
                                               float* __restrict__ xt,
                                               unsigned* __restrict__ pknext,
                                               float* __restrict__ acc) {
    int wid  = (blockIdx.x * blockDim.x + threadIdx.x) >> 6;
    int lane = threadIdx.x & 63;
    if (wid >= NN) return;
    int grp = lane >> 4, l16 = lane & 15;

    const unsigned* ph = pk + (size_t)wid * ROWD;
    uint4 hq = *(const uint4*)&ph[4 * l16];
    h2 hg0 = as_h2(hq.x), hi0 = as_h2(hq.y), hg1 = as_h2(hq.z), hi1 = as_h2(hq.w);

    int s = row_off[wid], eend = s + deg[wid];
    float sg = 0.f, si = 0.f;
    float g0 = 0.f, g1 = 0.f, g2 = 0.f, g3 = 0.f;
    float i0 = 0.f, i1 = 0.f, i2 = 0.f, i3 = 0.f;

    int e = s;
    for (; e + 7 < eend; e += 8) {
        int tA = csr[e + grp].x;
        int tB = csr[e + 4 + grp].x;
        const unsigned* pA = pk + (size_t)tA * ROWD;
        const unsigned* pB = pk + (size_t)tB * ROWD;
        uint4 qA = *(const uint4*)&pA[4 * l16];
        uint2 wA = *(const uint2*)&pA[64 + 2 * l16];
        uint4 qB = *(const uint4*)&pB[4 * l16];
        uint2 wB = *(const uint2*)&pB[64 + 2 * l16];
        float pgA = fdot2(hg0, as_h2(qA.x), fdot2(hg1, as_h2(qA.z), 0.f));
        float piA = fdot2(hi0, as_h2(qA.y), fdot2(hi1, as_h2(qA.w), 0.f));
        float pgB = fdot2(hg0, as_h2(qB.x), fdot2(hg1, as_h2(qB.z), 0.f));
        float piB = fdot2(hi0, as_h2(qB.y), fdot2(hi1, as_h2(qB.w), 0.f));
        #pragma unroll
        for (int m = 1; m <= 8; m <<= 1) {
            pgA += __shfl_xor(pgA, m); piA += __shfl_xor(piA, m);
            pgB += __shfl_xor(pgB, m); piB += __shfl_xor(piB, m);
        }
        float agA = fmaf(pgA, 0.5f, 0.5f), aiA = fmaf(piA, 0.5f, 0.5f);
        float agB = fmaf(pgB, 0.5f, 0.5f), aiB = fmaf(piB, 0.5f, 0.5f);
        sg += agA + agB; si += aiA + aiB;
        h2 xa0 = as_h2(wA.x), xa1 = as_h2(wA.y);
        h2 xb0 = as_h2(wB.x), xb1 = as_h2(wB.y);
        float xA[4] = {(float)xa0.x, (float)xa0.y, (float)xa1.x, (float)xa1.y};
        float xB[4] = {(float)xb0.x, (float)xb0.y, (float)xb1.x, (float)xb1.y};
        g0 = fmaf(agA, xA[0], g0); g1 = fmaf(agA, xA[1], g1);
        g2 = fmaf(agA, xA[2], g2); g3 = fmaf(agA, xA[3], g3);
        i0 = fmaf(aiA, xA[0], i0); i1 = fmaf(aiA, xA[1], i1);
        i2 = fmaf(aiA, xA[2], i2); i3 = fmaf(aiA, xA[3], i3);
        g0 = fmaf(agB, xB[0], g0); g1 = fmaf(agB, xB[1], g1);
        g2 = fmaf(agB, xB[2], g2); g3 = fmaf(agB, xB[3], g3);
        i0 = fmaf(aiB, xB[0], i0); i1 = fmaf(aiB, xB[1], i1);
        i2 = fmaf(aiB, xB[2], i2); i3 = fmaf(aiB, xB[3], i3);
    }
    for (; e < eend; e += 4) {
        int ee = e + grp;
        bool val = ee < eend;
        int t = csr[val ? ee : eend - 1].x;
        const unsigned* pr = pk + (size_t)t * ROWD;
        uint4 q = *(const uint4*)&pr[4 * l16];
        uint2 w = *(const uint2*)&pr[64 + 2 * l16];
        float pg = fdot2(hg0, as_h2(q.x), fdot2(hg1, as_h2(q.z), 0.f));
        float pi = fdot2(hi0, as_h2(q.y), fdot2(hi1, as_h2(q.w), 0.f));
        #pragma unroll
        for (int m = 1; m <= 8; m <<= 1) {
            pg += __shfl_xor(pg, m); pi += __shfl_xor(pi, m);
        }
        float ag = fmaf(pg, 0.5f, 0.5f), ai = fmaf(pi, 0.5f, 0.5f);
        if (!val) { ag = 0.f; ai = 0.f; }
        sg += ag; si += ai;
        h2 x0 = as_h2(w.x), x1 = as_h2(w.y);
        float xv[4] = {(float)x0.x, (float)x0.y, (float)x1.x, (float)x1.y};
        g0 = fmaf(ag, xv[0], g0); g1 = fmaf(ag, xv[1], g1);
        g2 = fmaf(ag, xv[2], g2); g3 = fmaf(ag, xv[3], g3);
        i0 = fmaf(ai, xv[0], i0); i1 = fmaf(ai, xv[1], i1);
        i2 = fmaf(ai, xv[2], i2); i3 = fmaf(ai, xv[3], i3);
    }

    #pragma unroll
    for (int m = 16; m <= 32; m <<= 1) {
        sg += __shfl_xor(sg, m); si += __shfl_xor(si, m);
        g0 += __shfl_xor(g0, m); g1 += __shfl_xor(g1, m);
        g2 += __shfl_xor(g2, m); g3 += __shfl_xor(g3, m);
        i0 += __shfl_xor(i0, m); i1 += __shfl_xor(i1, m);
        i2 += __shfl_xor(i2, m); i3 += __shfl_xor(i3, m);
    }

    if (grp == 0) {
        float invg = sg > 0.f ? 1.f / sg : 0.f;
        float invi = si > 0.f ? 1.f / si : 0.f;
        size_t bidx = (size_t)wid * 16 + l16;
        float4 b  = ((const float4*)base_)[bidx];
        float4 il = ((const float4*)(pknext + (size_t)wid * ROWD))[l16]; // raw intl
        float o0 = b.x + il.x + invg * g0 + invi * i0;
        float o1 = b.y + il.y + invg * g1 + invi * i1;
        float o2 = b.z + il.z + invg * g2 + invi * i2;
        float o3 = b.w + il.w + invg * g3 + invi * i3;
        float4 ov; ov.x = o0; ov.y = o1; ov.z = o2; ov.w = o3;
        ((float4*)xt)[bidx] = ov;
        *(uint2*)&pknext[(size_t)wid * ROWD + 64 + 2 * l16] =
            make_uint2(pkrtz(o0, o1), pkrtz(o2, o3));
        float4 a = ((float4*)acc)[bidx];
        a.x += o0; a.y += o1; a.z += o2; a.w += o3;
        ((float4*)acc)[bidx] = a;
    }
}

// ---------------- launch ----------------

extern "C" void kernel_launch(void* const* d_in, const int* in_sizes, int n_in,
                              void* d_out, int out_size, void* d_ws, size_t ws_size,
                              hipStream_t stream) {
    const float* emb   = (const float*)d_in[0];
    const float* Wu    = (const float*)d_in[1];
    const float* Wi    = (const float*)d_in[2];
    const int*   all_h = (const int*)d_in[3];
    const int*   all_t = (const int*)d_in[4];
    float*       acc   = (float*)d_out;

    char*  bp  = (char*)d_ws;
    size_t off = 0;
    auto take = [&](size_t bytes) -> char* {
        char* r = bp + off;
        off = (off + bytes + 255) & ~(size_t)255;
        return r;
    };
    int*      deg     = (int*)     take((size_t)NN * 4);
    int*      row_off = (int*)     take((size_t)NN * 4);
    int*      row_cur = (int*)     take((size_t)NN * 4);
    int*      counter = (int*)     take(256);
    float*    d_inv   = (float*)   take((size_t)NN * 4);
    int2*     csr     = (int2*)    take((size_t)NE * 8);
    unsigned* pkA     = (unsigned*)take((size_t)NN * ROWD * 4);
    unsigned* pkB     = (unsigned*)take((size_t)NN * ROWD * 4);
    float*    xt      = (float*)   take((size_t)NN * D * 4);
    float*    base_   = (float*)   take((size_t)NN * D * 4);
    float*    WtG     = (float*)   take((size_t)2 * D * KDIM * 4);
    (void)ws_size; (void)in_sizes; (void)n_in; (void)out_size;

    hipMemsetAsync(deg, 0, (size_t)NN * 4, stream);
    hipMemsetAsync(row_cur, 0, (size_t)NN * 4, stream);
    hipMemsetAsync(counter, 0, 256, stream);

    const int EB  = (NE + 255) / 256;
    const int NBK = (NN + 255) / 256;
    k_deg<<<EB, 256, 0, stream>>>(all_h, deg);
    k_rowoff<<<NBK, 256, 0, stream>>>(deg, counter, row_off, d_inv);
    k_scatter<<<EB, 256, 0, stream>>>(all_h, all_t, row_off, row_cur, d_inv, csr);

    k_init<<<(NN * 16 + 255) / 256, 256, 0, stream>>>(emb, xt, acc, pkA);
    k_wt<<<(2 * D * KDIM + 255) / 256, 256, 0, stream>>>(Wu, Wi, WtG);

    const int RB = (NN + 3) / 4;
    unsigned* cur = pkA;
    unsigned* nxt = pkB;
    for (int l = 0; l < 3; ++l) {
        k_mid<<<NINT + RB, 256, 0, stream>>>(row_off, deg, csr, cur, nxt,
                                             xt, Wu, Wi, WtG, base_);
        k_fused<<<RB, 256, 0, stream>>>(row_off, deg, csr, cur, base_, xt, nxt, acc);
        unsigned* tmp = cur; cur = nxt; nxt = tmp;
    }
}